// Round 9
// baseline (322.656 us; speedup 1.0000x reference)
//
#include <hip/hip_runtime.h>
#include <hip/hip_bf16.h>

#define ATT_SCALE 0.17677669529663687f   // 1/sqrt(32)

typedef __attribute__((ext_vector_type(8))) short short8v;
typedef __attribute__((ext_vector_type(4))) float f32x4;
typedef __attribute__((ext_vector_type(16))) float f32x16;

__device__ __forceinline__ short f2bf(float f) {
    unsigned u = __builtin_bit_cast(unsigned, f);
    u = u + 0x7fffu + ((u >> 16) & 1u);   // RNE
    return (short)(u >> 16);
}
__device__ __forceinline__ float bf2f(short s) {
    unsigned u = ((unsigned)(unsigned short)s) << 16;
    return __builtin_bit_cast(float, u);
}
__device__ __forceinline__ unsigned pk2(float lo, float hi) {
    return (unsigned)(unsigned short)f2bf(lo) |
           ((unsigned)(unsigned short)f2bf(hi) << 16);
}
__device__ __forceinline__ float lo16f(unsigned w) {
    return __builtin_bit_cast(float, w << 16);
}
__device__ __forceinline__ float hi16f(unsigned w) {
    return __builtin_bit_cast(float, w & 0xffff0000u);
}

// ---------------------------------------------------------------------------
// K0: one-time weight conversion. wbf = bf16{Wq*scale, Wk, Wv, Wg};
// wbbf = bf16 Wb; Wo -> hi/lo bf16 split.
// ---------------------------------------------------------------------------
__global__ __launch_bounds__(256) void k_wprep(
    const float* __restrict__ Wq, const float* __restrict__ Wk,
    const float* __restrict__ Wv, const float* __restrict__ Wg,
    const float* __restrict__ Wb, const float* __restrict__ Wo,
    unsigned short* __restrict__ wbf, unsigned short* __restrict__ wbbf,
    unsigned short* __restrict__ wohi, unsigned short* __restrict__ wolo)
{
    int idx = blockIdx.x * 256 + threadIdx.x;
    if (idx < 65536) {
        int m = idx >> 14, e = idx & 16383;
        float v;
        if (m == 0)      v = Wq[e] * ATT_SCALE;
        else if (m == 1) v = Wk[e];
        else if (m == 2) v = Wv[e];
        else             v = Wg[e];
        wbf[idx] = (unsigned short)f2bf(v);
    } else if (idx < 66048) {
        int e = idx - 65536;
        wbbf[e] = (unsigned short)f2bf(Wb[e]);
    } else if (idx < 82432) {
        int e = idx - 66048;
        float w = Wo[e];
        short hv = f2bf(w);
        wohi[e] = (unsigned short)hv;
        wolo[e] = (unsigned short)f2bf(w - bf2f(hv));
    }
}

// ---------------------------------------------------------------------------
// KA: LN + projections + bias. 512 threads = 8 waves, block = 128 positions.
// q/k bf16 head-major [h][pos][32]; V bf16 TRANSPOSED + key-bit-2<->3-swapped
// VT[h][x][d=32][perm(y)] (so attn PV consumes packed P dwords directly).
// g fp32 head-major. bias bf16 natural [h][j][k].
// ---------------------------------------------------------------------------
__global__ __launch_bounds__(512, 4) void k_lnproj(
    const float* __restrict__ z, const float* __restrict__ lnw,
    const float* __restrict__ lnb,
    const unsigned short* __restrict__ wbf, const unsigned short* __restrict__ wbbf,
    const float* __restrict__ bg,
    unsigned short* __restrict__ q_o, unsigned short* __restrict__ k_o,
    unsigned short* __restrict__ vt_o, float* __restrict__ g_o,
    unsigned short* __restrict__ bbf)
{
    __shared__ __align__(16) short zn[128][136];
    __shared__ __align__(16) short wstg[8][32][40];

    const int tid  = threadIdx.x;
    const int lane = tid & 63;
    const int wave = tid >> 6;
    const int l15  = lane & 15;
    const int g    = lane >> 4;
    const int wr   = wave >> 2;
    const int wc   = wave & 3;
    const long p0  = (long)blockIdx.x * 128;
    const int xq   = (int)(p0 >> 8);
    const int y0   = (int)(p0 & 255);

    // ---- LN ----
    {
        const int r = tid >> 2, q4 = tid & 3;
        const float* zrow = z + (p0 + r) * 128 + q4 * 32;
        float4 xv[8];
        float s1 = 0.f, s2 = 0.f;
#pragma unroll
        for (int m = 0; m < 8; ++m) {
            xv[m] = *(const float4*)(zrow + m * 4);
            s1 += xv[m].x + xv[m].y + xv[m].z + xv[m].w;
            s2 += xv[m].x * xv[m].x + xv[m].y * xv[m].y +
                  xv[m].z * xv[m].z + xv[m].w * xv[m].w;
        }
        s1 += __shfl_xor(s1, 1); s2 += __shfl_xor(s2, 1);
        s1 += __shfl_xor(s1, 2); s2 += __shfl_xor(s2, 2);
        float mu  = s1 * 0.0078125f;
        float inv = rsqrtf(s2 * 0.0078125f - mu * mu + 1e-5f);
#pragma unroll
        for (int mm = 0; mm < 4; ++mm) {
            float4 a = xv[2 * mm], b = xv[2 * mm + 1];
            const float* wp = lnw + q4 * 32 + mm * 8;
            const float* bp = lnb + q4 * 32 + mm * 8;
            float4 w0 = *(const float4*)wp, w1 = *(const float4*)(wp + 4);
            float4 b0 = *(const float4*)bp, b1 = *(const float4*)(bp + 4);
            uint4 uu;
            uu.x = pk2((a.x - mu) * inv * w0.x + b0.x, (a.y - mu) * inv * w0.y + b0.y);
            uu.y = pk2((a.z - mu) * inv * w0.z + b0.z, (a.w - mu) * inv * w0.w + b0.w);
            uu.z = pk2((b.x - mu) * inv * w1.x + b1.x, (b.y - mu) * inv * w1.y + b1.y);
            uu.w = pk2((b.z - mu) * inv * w1.z + b1.z, (b.w - mu) * inv * w1.w + b1.w);
            *(uint4*)&zn[r][q4 * 32 + mm * 8] = uu;
        }
    }
    __syncthreads();

    // ---- pair bias (bf16 out) ----
    if (wc == 0) {
        const unsigned short* wbp = wbbf + (l15 & 3) * 128;
        short8v wb[4];
#pragma unroll
        for (int ks = 0; ks < 4; ++ks)
            wb[ks] = *(const short8v*)(wbp + ks * 32 + g * 8);
        f32x4 bacc[4];
#pragma unroll
        for (int rt = 0; rt < 4; ++rt) bacc[rt] = (f32x4){0.f, 0.f, 0.f, 0.f};
#pragma unroll
        for (int ks = 0; ks < 4; ++ks)
#pragma unroll
            for (int rt = 0; rt < 4; ++rt) {
                short8v a = *(const short8v*)&zn[wr * 64 + rt * 16 + l15][ks * 32 + g * 8];
                bacc[rt] = __builtin_amdgcn_mfma_f32_16x16x32_bf16(a, wb[ks], bacc[rt], 0, 0, 0);
            }
        if (l15 < 4) {
#pragma unroll
            for (int rt = 0; rt < 4; ++rt) {
                uint2 w;
                w.x = pk2(bacc[rt][0], bacc[rt][1]);
                w.y = pk2(bacc[rt][2], bacc[rt][3]);
                *(uint2*)(bbf + (long)l15 * 65536 + xq * 256 + y0 +
                          wr * 64 + rt * 16 + g * 4) = w;
            }
        }
    }

    // ---- 4 projection matrices ----
    for (int wsel = 0; wsel < 4; ++wsel) {
        const unsigned short* __restrict__ W = wbf + wsel * 16384;
        f32x4 acc[4][2];
#pragma unroll
        for (int rt = 0; rt < 4; ++rt) {
            acc[rt][0] = (f32x4){0.f, 0.f, 0.f, 0.f};
            acc[rt][1] = (f32x4){0.f, 0.f, 0.f, 0.f};
        }
#pragma unroll
        for (int ks = 0; ks < 4; ++ks) {
            short8v b0 = *(const short8v*)(W + (wc * 32 + l15) * 128 + ks * 32 + g * 8);
            short8v b1 = *(const short8v*)(W + (wc * 32 + 16 + l15) * 128 + ks * 32 + g * 8);
#pragma unroll
            for (int rt = 0; rt < 4; ++rt) {
                short8v a = *(const short8v*)&zn[wr * 64 + rt * 16 + l15][ks * 32 + g * 8];
                acc[rt][0] = __builtin_amdgcn_mfma_f32_16x16x32_bf16(a, b0, acc[rt][0], 0, 0, 0);
                acc[rt][1] = __builtin_amdgcn_mfma_f32_16x16x32_bf16(a, b1, acc[rt][1], 0, 0, 0);
            }
        }

        if (wsel == 3) {
#pragma unroll
            for (int ct = 0; ct < 2; ++ct) {
                float bgc = bg[wc * 32 + ct * 16 + l15];
#pragma unroll
                for (int rt = 0; rt < 4; ++rt)
#pragma unroll
                    for (int r = 0; r < 4; ++r) {
                        float val = acc[rt][ct][r] + bgc;
                        g_o[((long)wc * 65536 + p0 + wr * 64 + rt * 16 + g * 4 + r) * 32 +
                            ct * 16 + l15] = 1.0f / (1.0f + __expf(-val));
                    }
            }
        } else if (wsel == 2) {
            // V: stage transposed, copy out with key-bit-2<->3 swap (per 32 keys)
#pragma unroll
            for (int pair = 0; pair < 2; ++pair) {
#pragma unroll
                for (int rt2 = 0; rt2 < 2; ++rt2)
#pragma unroll
                    for (int ct = 0; ct < 2; ++ct)
#pragma unroll
                        for (int r = 0; r < 4; ++r)
                            wstg[wave][ct * 16 + l15][rt2 * 16 + g * 4 + r] =
                                f2bf(acc[pair * 2 + rt2][ct][r]);
#pragma unroll
                for (int e = 0; e < 4; ++e) {
                    int idx = e * 64 + lane;
                    int d = idx >> 3, k4 = idx & 7;
                    int k4p = ((k4 & 1) << 1) | ((k4 >> 1) & 1) | (k4 & 4);
                    short4 sv = *(const short4*)&wstg[wave][d][k4 * 4];
                    *(short4*)(vt_o + (((long)wc * 256 + xq) * 32 + d) * 256 +
                               y0 + wr * 64 + pair * 32 + k4p * 4) = sv;
                }
            }
        } else {
            unsigned short* __restrict__ O = (wsel == 0) ? q_o : k_o;
#pragma unroll
            for (int pair = 0; pair < 2; ++pair) {
#pragma unroll
                for (int rt2 = 0; rt2 < 2; ++rt2)
#pragma unroll
                    for (int ct = 0; ct < 2; ++ct)
#pragma unroll
                        for (int r = 0; r < 4; ++r)
                            wstg[wave][rt2 * 16 + g * 4 + r][ct * 16 + l15] =
                                f2bf(acc[pair * 2 + rt2][ct][r]);
#pragma unroll
                for (int ps = 0; ps < 2; ++ps) {
                    int idx = ps * 64 + lane;
                    int lr = idx >> 2, ch = (idx & 3) * 8;
                    short8v vv = *(const short8v*)&wstg[wave][lr][ch];
                    *(short8v*)(O + ((long)wc * 65536 + p0 + wr * 64 + pair * 32 + lr) * 32 + ch) = vv;
                }
            }
        }
    }
}

// ---------------------------------------------------------------------------
// KB: attention, 32x32 MFMA, softmax fully in registers (no P LDS).
// Per wave: 2 q-blocks of 32 queries. S^T tile: lane = query col, 16 S values
// in consecutive-key pairs; exp+pack in-register; packed dwords are the PV
// B-fragment directly (V^T stored with key bits 2<->3 swapped). 4 blocks/CU.
// ---------------------------------------------------------------------------
__global__ __launch_bounds__(256, 4) void k_attn_mfma(
    const unsigned short* __restrict__ q_ws, const unsigned short* __restrict__ k_ws,
    const unsigned short* __restrict__ vt_ws, const float* __restrict__ g_ws,
    const unsigned short* __restrict__ bbf, const float* __restrict__ pm,
    unsigned short* __restrict__ ohi, unsigned short* __restrict__ olo)
{
    __shared__ __align__(16) short Ksh[256][40];    // 20.5 KB
    __shared__ __align__(16) short VTsh[32][264];   // 16.9 KB
    __shared__ float pmsh[256];

    const int tid  = threadIdx.x;
    const int lane = tid & 63;
    const int wave = tid >> 6;
    const int l31  = lane & 31;
    const int hi   = lane >> 5;
    const int h = blockIdx.x & 3;
    const int i = blockIdx.x >> 2;
    const long hbase  = ((long)h * 65536 + (long)i * 256) * 32;
    const long vtbase = ((long)h * 256 + i) * 8192;

    pmsh[tid] = pm[i * 256 + tid];
#pragma unroll
    for (int pass = 0; pass < 4; ++pass) {
        int idx = pass * 256 + tid;          // 0..1023
        *(short8v*)&Ksh[idx >> 2][(idx & 3) * 8] =
            *(const short8v*)(k_ws + hbase + idx * 8);
        *(short8v*)&VTsh[idx >> 5][(idx & 31) * 8] =
            *(const short8v*)(vt_ws + vtbase + idx * 8);
    }
    __syncthreads();

    bool ok4 = true;
#pragma unroll
    for (int e = 0; e < 4; ++e) ok4 = ok4 && (pmsh[lane * 4 + e] > 0.5f);
    const bool allok = __all(ok4);

    const f32x16 zero16 = {0.f,0.f,0.f,0.f,0.f,0.f,0.f,0.f,
                           0.f,0.f,0.f,0.f,0.f,0.f,0.f,0.f};

    for (int qi = 0; qi < 2; ++qi) {
        const int qb = wave * 2 + qi;
        const int ql = qb * 32 + l31;

        short8v bq0 = *(const short8v*)(q_ws + hbase + (long)ql * 32 + hi * 8);
        short8v bq1 = *(const short8v*)(q_ws + hbase + (long)ql * 32 + 16 + hi * 8);
        const bool rowok = pmsh[ql] > 0.5f;
        const unsigned short* bp_base = bbf + ((long)h << 16) + (long)ql * 256 + hi * 4;

        f32x16 oacc = zero16;
        float lsum = 0.f;

#pragma unroll
        for (int t = 0; t < 8; ++t) {
            // bias loads (decoupled)
            uint2 bw0 = *(const uint2*)(bp_base + t * 32);
            uint2 bw1 = *(const uint2*)(bp_base + t * 32 + 8);
            uint2 bw2 = *(const uint2*)(bp_base + t * 32 + 16);
            uint2 bw3 = *(const uint2*)(bp_base + t * 32 + 24);

            short8v ka0 = *(const short8v*)&Ksh[t * 32 + l31][hi * 8];
            short8v ka1 = *(const short8v*)&Ksh[t * 32 + l31][16 + hi * 8];
            f32x16 s = __builtin_amdgcn_mfma_f32_32x32x16_bf16(ka0, bq0, zero16, 0, 0, 0);
            s = __builtin_amdgcn_mfma_f32_32x32x16_bf16(ka1, bq1, s, 0, 0, 0);

            float p[16];
            if (allok) {
                p[0]  = __expf(s[0]  + lo16f(bw0.x));
                p[1]  = __expf(s[1]  + hi16f(bw0.x));
                p[2]  = __expf(s[2]  + lo16f(bw0.y));
                p[3]  = __expf(s[3]  + hi16f(bw0.y));
                p[4]  = __expf(s[4]  + lo16f(bw1.x));
                p[5]  = __expf(s[5]  + hi16f(bw1.x));
                p[6]  = __expf(s[6]  + lo16f(bw1.y));
                p[7]  = __expf(s[7]  + hi16f(bw1.y));
                p[8]  = __expf(s[8]  + lo16f(bw2.x));
                p[9]  = __expf(s[9]  + hi16f(bw2.x));
                p[10] = __expf(s[10] + lo16f(bw2.y));
                p[11] = __expf(s[11] + hi16f(bw2.y));
                p[12] = __expf(s[12] + lo16f(bw3.x));
                p[13] = __expf(s[13] + hi16f(bw3.x));
                p[14] = __expf(s[14] + lo16f(bw3.y));
                p[15] = __expf(s[15] + hi16f(bw3.y));
            } else {
                const uint2 bws[4] = {bw0, bw1, bw2, bw3};
#pragma unroll
                for (int n = 0; n < 4; ++n) {
                    f32x4 ma = *(const f32x4*)&pmsh[t * 32 + n * 8 + hi * 4];
#pragma unroll
                    for (int j = 0; j < 4; ++j) {
                        float badd = (j == 0) ? lo16f(bws[n].x) :
                                     (j == 1) ? hi16f(bws[n].x) :
                                     (j == 2) ? lo16f(bws[n].y) : hi16f(bws[n].y);
                        float mv = (ma[j] > 0.5f) ? 0.0f : -1e9f;
                        p[4 * n + j] = __expf(rowok ? s[4 * n + j] + badd + mv : 0.0f);
                    }
                }
            }
#pragma unroll
            for (int e = 0; e < 16; ++e) lsum += p[e];

            uint4 w0, w1;
            w0.x = pk2(p[0], p[1]);  w0.y = pk2(p[2], p[3]);
            w0.z = pk2(p[4], p[5]);  w0.w = pk2(p[6], p[7]);
            w1.x = pk2(p[8], p[9]);  w1.y = pk2(p[10], p[11]);
            w1.z = pk2(p[12], p[13]); w1.w = pk2(p[14], p[15]);
            short8v pb0 = *(short8v*)&w0;
            short8v pb1 = *(short8v*)&w1;

            short8v va0 = *(const short8v*)&VTsh[l31][t * 32 + hi * 8];
            short8v va1 = *(const short8v*)&VTsh[l31][t * 32 + 16 + hi * 8];
            oacc = __builtin_amdgcn_mfma_f32_32x32x16_bf16(va0, pb0, oacc, 0, 0, 0);
            oacc = __builtin_amdgcn_mfma_f32_32x32x16_bf16(va1, pb1, oacc, 0, 0, 0);
        }

        lsum += __shfl_xor(lsum, 32);
        const float linv = 1.0f / lsum;

        const long grow = hbase + (long)ql * 32;
        const long orow = (long)(i * 256 + ql) * 128 + h * 32;
#pragma unroll
        for (int n = 0; n < 4; ++n) {
            int dbase = n * 8 + hi * 4;
            float4 g4 = *(const float4*)(g_ws + grow + dbase);
            float v0 = oacc[4 * n + 0] * linv * g4.x;
            float v1 = oacc[4 * n + 1] * linv * g4.y;
            float v2 = oacc[4 * n + 2] * linv * g4.z;
            float v3 = oacc[4 * n + 3] * linv * g4.w;
            short h0 = f2bf(v0), h1 = f2bf(v1), h2 = f2bf(v2), h3 = f2bf(v3);
            short4 sh = {h0, h1, h2, h3};
            short4 sl = {f2bf(v0 - bf2f(h0)), f2bf(v1 - bf2f(h1)),
                         f2bf(v2 - bf2f(h2)), f2bf(v3 - bf2f(h3))};
            *(short4*)(ohi + orow + dbase) = sh;
            *(short4*)(olo + orow + dbase) = sl;
        }
    }
}

// ---------------------------------------------------------------------------
// KC: out = o @ Wo^T + bo. o pre-split hi/lo bf16 -> pure loads+MFMA.
// ---------------------------------------------------------------------------
__global__ __launch_bounds__(512, 4) void k_outproj(
    const unsigned short* __restrict__ ohi, const unsigned short* __restrict__ olo,
    const unsigned short* __restrict__ wohi, const unsigned short* __restrict__ wolo,
    const float* __restrict__ bo, float* __restrict__ out)
{
    const int tid  = threadIdx.x;
    const int lane = tid & 63;
    const int wave = tid >> 6;
    const int l15  = lane & 15;
    const int g    = lane >> 4;
    const int wr   = wave >> 2;
    const int wc   = wave & 3;
    const long p0  = (long)blockIdx.x * 128;

    f32x4 acc[4][2];
#pragma unroll
    for (int rt = 0; rt < 4; ++rt) {
        acc[rt][0] = (f32x4){0.f, 0.f, 0.f, 0.f};
        acc[rt][1] = (f32x4){0.f, 0.f, 0.f, 0.f};
    }

#pragma unroll
    for (int ks = 0; ks < 4; ++ks) {
        const int wof = ks * 32 + g * 8;
        short8v bh0 = *(const short8v*)(wohi + (wc * 32 + l15) * 128 + wof);
        short8v bh1 = *(const short8v*)(wohi + (wc * 32 + 16 + l15) * 128 + wof);
        short8v bl0 = *(const short8v*)(wolo + (wc * 32 + l15) * 128 + wof);
        short8v bl1 = *(const short8v*)(wolo + (wc * 32 + 16 + l15) * 128 + wof);
#pragma unroll
        for (int rt = 0; rt < 4; ++rt) {
            long aoff = (p0 + wr * 64 + rt * 16 + l15) * 128 + ks * 32 + g * 8;
            short8v ah = *(const short8v*)(ohi + aoff);
            short8v al = *(const short8v*)(olo + aoff);
            acc[rt][0] = __builtin_amdgcn_mfma_f32_16x16x32_bf16(ah, bh0, acc[rt][0], 0, 0, 0);
            acc[rt][0] = __builtin_amdgcn_mfma_f32_16x16x32_bf16(ah, bl0, acc[rt][0], 0, 0, 0);
            acc[rt][0] = __builtin_amdgcn_mfma_f32_16x16x32_bf16(al, bh0, acc[rt][0], 0, 0, 0);
            acc[rt][1] = __builtin_amdgcn_mfma_f32_16x16x32_bf16(ah, bh1, acc[rt][1], 0, 0, 0);
            acc[rt][1] = __builtin_amdgcn_mfma_f32_16x16x32_bf16(ah, bl1, acc[rt][1], 0, 0, 0);
            acc[rt][1] = __builtin_amdgcn_mfma_f32_16x16x32_bf16(al, bh1, acc[rt][1], 0, 0, 0);
        }
    }

#pragma unroll
    for (int ct = 0; ct < 2; ++ct) {
        float bv = bo[wc * 32 + ct * 16 + l15];
#pragma unroll
        for (int rt = 0; rt < 4; ++rt)
#pragma unroll
            for (int r = 0; r < 4; ++r)
                out[(p0 + wr * 64 + rt * 16 + g * 4 + r) * 128 +
                    wc * 32 + ct * 16 + l15] = acc[rt][ct][r] + bv;
    }
}

// ---------------------------------------------------------------------------
extern "C" void kernel_launch(void* const* d_in, const int* in_sizes, int n_in,
                              void* d_out, int out_size, void* d_ws, size_t ws_size,
                              hipStream_t stream) {
    const float* z   = (const float*)d_in[0];
    const float* pm  = (const float*)d_in[1];
    const float* lnw = (const float*)d_in[2];
    const float* lnb = (const float*)d_in[3];
    const float* Wq  = (const float*)d_in[4];
    const float* Wk  = (const float*)d_in[5];
    const float* Wv  = (const float*)d_in[6];
    const float* Wb  = (const float*)d_in[7];
    const float* Wg  = (const float*)d_in[8];
    const float* bg  = (const float*)d_in[9];
    const float* Wo  = (const float*)d_in[10];
    const float* bo  = (const float*)d_in[11];
    float* out = (float*)d_out;

    unsigned short* wsS  = (unsigned short*)d_ws;
    unsigned short* wbf  = wsS;                   // 65536
    unsigned short* wbbf = wsS + 65536;           // 512
    unsigned short* wohi = wsS + 66048;           // 16384
    unsigned short* wolo = wsS + 82432;           // 16384
    unsigned short* bbf  = wsS + 98816;           // 262144 bf16 [4][256][256]
    unsigned short* qb   = wsS + 360960;          // 8388608 bf16 [4][65536][32]
    unsigned short* kb   = qb + 8388608;
    unsigned short* vtb  = kb + 8388608;          // [4][256][32][256] (perm keys)
    unsigned short* ohiw = vtb + 8388608;         // 8388608 bf16 [65536][128]
    unsigned short* olow = ohiw + 8388608;        // 8388608
    float* gws = (float*)(olow + 8388608);        // 8388608 fp32 [4][65536][32]

    k_wprep<<<322, 256, 0, stream>>>(Wq, Wk, Wv, Wg, Wb, Wo, wbf, wbbf, wohi, wolo);
    k_lnproj<<<512, 512, 0, stream>>>(z, lnw, lnb, wbf, wbbf, bg, qb, kb, vtb, gws, bbf);
    k_attn_mfma<<<1024, 256, 0, stream>>>(qb, kb, vtb, gws, bbf, pm, ohiw, olow);
    k_outproj<<<512, 512, 0, stream>>>(ohiw, olow, wohi, wolo, bo, out);
}

// Round 10
// 121.255 us; speedup vs baseline: 2.6610x; 2.6610x over previous
//
#include <hip/hip_runtime.h>
#include <hip/hip_bf16.h>

#define ATT_SCALE 0.17677669529663687f   // 1/sqrt(32)

typedef __attribute__((ext_vector_type(8))) short short8v;
typedef __attribute__((ext_vector_type(4))) float f32x4;
typedef __attribute__((ext_vector_type(16))) float f32x16;

__device__ __forceinline__ short f2bf(float f) {
    unsigned u = __builtin_bit_cast(unsigned, f);
    u = u + 0x7fffu + ((u >> 16) & 1u);   // RNE
    return (short)(u >> 16);
}
__device__ __forceinline__ float bf2f(short s) {
    unsigned u = ((unsigned)(unsigned short)s) << 16;
    return __builtin_bit_cast(float, u);
}
__device__ __forceinline__ unsigned pk2(float lo, float hi) {
    return (unsigned)(unsigned short)f2bf(lo) |
           ((unsigned)(unsigned short)f2bf(hi) << 16);
}
__device__ __forceinline__ float lo16f(unsigned w) {
    return __builtin_bit_cast(float, w << 16);
}
__device__ __forceinline__ float hi16f(unsigned w) {
    return __builtin_bit_cast(float, w & 0xffff0000u);
}

// ---------------------------------------------------------------------------
// K0: one-time weight conversion. wbf = bf16{Wq*scale, Wk, Wv, Wg};
// wbbf = bf16 Wb; Wo -> hi/lo bf16 split.
// ---------------------------------------------------------------------------
__global__ __launch_bounds__(256) void k_wprep(
    const float* __restrict__ Wq, const float* __restrict__ Wk,
    const float* __restrict__ Wv, const float* __restrict__ Wg,
    const float* __restrict__ Wb, const float* __restrict__ Wo,
    unsigned short* __restrict__ wbf, unsigned short* __restrict__ wbbf,
    unsigned short* __restrict__ wohi, unsigned short* __restrict__ wolo)
{
    int idx = blockIdx.x * 256 + threadIdx.x;
    if (idx < 65536) {
        int m = idx >> 14, e = idx & 16383;
        float v;
        if (m == 0)      v = Wq[e] * ATT_SCALE;
        else if (m == 1) v = Wk[e];
        else if (m == 2) v = Wv[e];
        else             v = Wg[e];
        wbf[idx] = (unsigned short)f2bf(v);
    } else if (idx < 66048) {
        int e = idx - 65536;
        wbbf[e] = (unsigned short)f2bf(Wb[e]);
    } else if (idx < 82432) {
        int e = idx - 66048;
        float w = Wo[e];
        short hv = f2bf(w);
        wohi[e] = (unsigned short)hv;
        wolo[e] = (unsigned short)f2bf(w - bf2f(hv));
    }
}

// ---------------------------------------------------------------------------
// KA: LN + projections + bias. 512 threads = 8 waves, block = 128 positions.
// q/k bf16 head-major [h][pos][32]; V bf16 TRANSPOSED + key-bit-2<->3-swapped
// VT[h][x][d=32][perm(y)] (so attn PV consumes packed P dwords directly).
// g fp32 head-major. bias bf16 natural [h][j][k].
// ---------------------------------------------------------------------------
__global__ __launch_bounds__(512, 4) void k_lnproj(
    const float* __restrict__ z, const float* __restrict__ lnw,
    const float* __restrict__ lnb,
    const unsigned short* __restrict__ wbf, const unsigned short* __restrict__ wbbf,
    const float* __restrict__ bg,
    unsigned short* __restrict__ q_o, unsigned short* __restrict__ k_o,
    unsigned short* __restrict__ vt_o, float* __restrict__ g_o,
    unsigned short* __restrict__ bbf)
{
    __shared__ __align__(16) short zn[128][136];
    __shared__ __align__(16) short wstg[8][32][40];

    const int tid  = threadIdx.x;
    const int lane = tid & 63;
    const int wave = tid >> 6;
    const int l15  = lane & 15;
    const int g    = lane >> 4;
    const int wr   = wave >> 2;
    const int wc   = wave & 3;
    const long p0  = (long)blockIdx.x * 128;
    const int xq   = (int)(p0 >> 8);
    const int y0   = (int)(p0 & 255);

    // ---- LN ----
    {
        const int r = tid >> 2, q4 = tid & 3;
        const float* zrow = z + (p0 + r) * 128 + q4 * 32;
        float4 xv[8];
        float s1 = 0.f, s2 = 0.f;
#pragma unroll
        for (int m = 0; m < 8; ++m) {
            xv[m] = *(const float4*)(zrow + m * 4);
            s1 += xv[m].x + xv[m].y + xv[m].z + xv[m].w;
            s2 += xv[m].x * xv[m].x + xv[m].y * xv[m].y +
                  xv[m].z * xv[m].z + xv[m].w * xv[m].w;
        }
        s1 += __shfl_xor(s1, 1); s2 += __shfl_xor(s2, 1);
        s1 += __shfl_xor(s1, 2); s2 += __shfl_xor(s2, 2);
        float mu  = s1 * 0.0078125f;
        float inv = rsqrtf(s2 * 0.0078125f - mu * mu + 1e-5f);
#pragma unroll
        for (int mm = 0; mm < 4; ++mm) {
            float4 a = xv[2 * mm], b = xv[2 * mm + 1];
            const float* wp = lnw + q4 * 32 + mm * 8;
            const float* bp = lnb + q4 * 32 + mm * 8;
            float4 w0 = *(const float4*)wp, w1 = *(const float4*)(wp + 4);
            float4 b0 = *(const float4*)bp, b1 = *(const float4*)(bp + 4);
            uint4 uu;
            uu.x = pk2((a.x - mu) * inv * w0.x + b0.x, (a.y - mu) * inv * w0.y + b0.y);
            uu.y = pk2((a.z - mu) * inv * w0.z + b0.z, (a.w - mu) * inv * w0.w + b0.w);
            uu.z = pk2((b.x - mu) * inv * w1.x + b1.x, (b.y - mu) * inv * w1.y + b1.y);
            uu.w = pk2((b.z - mu) * inv * w1.z + b1.z, (b.w - mu) * inv * w1.w + b1.w);
            *(uint4*)&zn[r][q4 * 32 + mm * 8] = uu;
        }
    }
    __syncthreads();

    // ---- pair bias (bf16 out) ----
    if (wc == 0) {
        const unsigned short* wbp = wbbf + (l15 & 3) * 128;
        short8v wb[4];
#pragma unroll
        for (int ks = 0; ks < 4; ++ks)
            wb[ks] = *(const short8v*)(wbp + ks * 32 + g * 8);
        f32x4 bacc[4];
#pragma unroll
        for (int rt = 0; rt < 4; ++rt) bacc[rt] = (f32x4){0.f, 0.f, 0.f, 0.f};
#pragma unroll
        for (int ks = 0; ks < 4; ++ks)
#pragma unroll
            for (int rt = 0; rt < 4; ++rt) {
                short8v a = *(const short8v*)&zn[wr * 64 + rt * 16 + l15][ks * 32 + g * 8];
                bacc[rt] = __builtin_amdgcn_mfma_f32_16x16x32_bf16(a, wb[ks], bacc[rt], 0, 0, 0);
            }
        if (l15 < 4) {
#pragma unroll
            for (int rt = 0; rt < 4; ++rt) {
                uint2 w;
                w.x = pk2(bacc[rt][0], bacc[rt][1]);
                w.y = pk2(bacc[rt][2], bacc[rt][3]);
                *(uint2*)(bbf + (long)l15 * 65536 + xq * 256 + y0 +
                          wr * 64 + rt * 16 + g * 4) = w;
            }
        }
    }

    // ---- 4 projection matrices ----
    for (int wsel = 0; wsel < 4; ++wsel) {
        const unsigned short* __restrict__ W = wbf + wsel * 16384;
        f32x4 acc[4][2];
#pragma unroll
        for (int rt = 0; rt < 4; ++rt) {
            acc[rt][0] = (f32x4){0.f, 0.f, 0.f, 0.f};
            acc[rt][1] = (f32x4){0.f, 0.f, 0.f, 0.f};
        }
#pragma unroll
        for (int ks = 0; ks < 4; ++ks) {
            short8v b0 = *(const short8v*)(W + (wc * 32 + l15) * 128 + ks * 32 + g * 8);
            short8v b1 = *(const short8v*)(W + (wc * 32 + 16 + l15) * 128 + ks * 32 + g * 8);
#pragma unroll
            for (int rt = 0; rt < 4; ++rt) {
                short8v a = *(const short8v*)&zn[wr * 64 + rt * 16 + l15][ks * 32 + g * 8];
                acc[rt][0] = __builtin_amdgcn_mfma_f32_16x16x32_bf16(a, b0, acc[rt][0], 0, 0, 0);
                acc[rt][1] = __builtin_amdgcn_mfma_f32_16x16x32_bf16(a, b1, acc[rt][1], 0, 0, 0);
            }
        }

        if (wsel == 3) {
#pragma unroll
            for (int ct = 0; ct < 2; ++ct) {
                float bgc = bg[wc * 32 + ct * 16 + l15];
#pragma unroll
                for (int rt = 0; rt < 4; ++rt)
#pragma unroll
                    for (int r = 0; r < 4; ++r) {
                        float val = acc[rt][ct][r] + bgc;
                        g_o[((long)wc * 65536 + p0 + wr * 64 + rt * 16 + g * 4 + r) * 32 +
                            ct * 16 + l15] = 1.0f / (1.0f + __expf(-val));
                    }
            }
        } else if (wsel == 2) {
            // V: stage transposed, copy out with key-bit-2<->3 swap (per 32 keys)
#pragma unroll
            for (int pair = 0; pair < 2; ++pair) {
#pragma unroll
                for (int rt2 = 0; rt2 < 2; ++rt2)
#pragma unroll
                    for (int ct = 0; ct < 2; ++ct)
#pragma unroll
                        for (int r = 0; r < 4; ++r)
                            wstg[wave][ct * 16 + l15][rt2 * 16 + g * 4 + r] =
                                f2bf(acc[pair * 2 + rt2][ct][r]);
#pragma unroll
                for (int e = 0; e < 4; ++e) {
                    int idx = e * 64 + lane;
                    int d = idx >> 3, k4 = idx & 7;
                    int k4p = ((k4 & 1) << 1) | ((k4 >> 1) & 1) | (k4 & 4);
                    short4 sv = *(const short4*)&wstg[wave][d][k4 * 4];
                    *(short4*)(vt_o + (((long)wc * 256 + xq) * 32 + d) * 256 +
                               y0 + wr * 64 + pair * 32 + k4p * 4) = sv;
                }
            }
        } else {
            unsigned short* __restrict__ O = (wsel == 0) ? q_o : k_o;
#pragma unroll
            for (int pair = 0; pair < 2; ++pair) {
#pragma unroll
                for (int rt2 = 0; rt2 < 2; ++rt2)
#pragma unroll
                    for (int ct = 0; ct < 2; ++ct)
#pragma unroll
                        for (int r = 0; r < 4; ++r)
                            wstg[wave][rt2 * 16 + g * 4 + r][ct * 16 + l15] =
                                f2bf(acc[pair * 2 + rt2][ct][r]);
#pragma unroll
                for (int ps = 0; ps < 2; ++ps) {
                    int idx = ps * 64 + lane;
                    int lr = idx >> 2, ch = (idx & 3) * 8;
                    short8v vv = *(const short8v*)&wstg[wave][lr][ch];
                    *(short8v*)(O + ((long)wc * 65536 + p0 + wr * 64 + pair * 32 + lr) * 32 + ch) = vv;
                }
            }
        }
    }
}

// ---------------------------------------------------------------------------
// KB: attention, 32x32 MFMA, softmax fully in registers (no P LDS).
// launch_bounds(256,2): ~200 VGPR working set MUST NOT spill (R9 lesson:
// (256,4) forced a 64-VGPR cap -> 450 MB scratch traffic, 5x slowdown).
// ---------------------------------------------------------------------------
__global__ __launch_bounds__(256, 2) void k_attn_mfma(
    const unsigned short* __restrict__ q_ws, const unsigned short* __restrict__ k_ws,
    const unsigned short* __restrict__ vt_ws, const float* __restrict__ g_ws,
    const unsigned short* __restrict__ bbf, const float* __restrict__ pm,
    unsigned short* __restrict__ ohi, unsigned short* __restrict__ olo)
{
    __shared__ __align__(16) short Ksh[256][40];    // 20.5 KB
    __shared__ __align__(16) short VTsh[32][264];   // 16.9 KB
    __shared__ float pmsh[256];

    const int tid  = threadIdx.x;
    const int lane = tid & 63;
    const int wave = tid >> 6;
    const int l31  = lane & 31;
    const int hi   = lane >> 5;
    const int h = blockIdx.x & 3;
    const int i = blockIdx.x >> 2;
    const long hbase  = ((long)h * 65536 + (long)i * 256) * 32;
    const long vtbase = ((long)h * 256 + i) * 8192;

    pmsh[tid] = pm[i * 256 + tid];
#pragma unroll
    for (int pass = 0; pass < 4; ++pass) {
        int idx = pass * 256 + tid;          // 0..1023
        *(short8v*)&Ksh[idx >> 2][(idx & 3) * 8] =
            *(const short8v*)(k_ws + hbase + idx * 8);
        *(short8v*)&VTsh[idx >> 5][(idx & 31) * 8] =
            *(const short8v*)(vt_ws + vtbase + idx * 8);
    }
    __syncthreads();

    bool ok4 = true;
#pragma unroll
    for (int e = 0; e < 4; ++e) ok4 = ok4 && (pmsh[lane * 4 + e] > 0.5f);
    const bool allok = __all(ok4);

    const f32x16 zero16 = {0.f,0.f,0.f,0.f,0.f,0.f,0.f,0.f,
                           0.f,0.f,0.f,0.f,0.f,0.f,0.f,0.f};

    for (int qi = 0; qi < 2; ++qi) {
        const int qb = wave * 2 + qi;
        const int ql = qb * 32 + l31;

        short8v bq0 = *(const short8v*)(q_ws + hbase + (long)ql * 32 + hi * 8);
        short8v bq1 = *(const short8v*)(q_ws + hbase + (long)ql * 32 + 16 + hi * 8);
        const bool rowok = pmsh[ql] > 0.5f;
        const unsigned short* bp_base = bbf + ((long)h << 16) + (long)ql * 256 + hi * 4;

        f32x16 oacc = zero16;
        float lsum = 0.f;

#pragma unroll
        for (int t = 0; t < 8; ++t) {
            uint2 bw0 = *(const uint2*)(bp_base + t * 32);
            uint2 bw1 = *(const uint2*)(bp_base + t * 32 + 8);
            uint2 bw2 = *(const uint2*)(bp_base + t * 32 + 16);
            uint2 bw3 = *(const uint2*)(bp_base + t * 32 + 24);

            short8v ka0 = *(const short8v*)&Ksh[t * 32 + l31][hi * 8];
            short8v ka1 = *(const short8v*)&Ksh[t * 32 + l31][16 + hi * 8];
            f32x16 s = __builtin_amdgcn_mfma_f32_32x32x16_bf16(ka0, bq0, zero16, 0, 0, 0);
            s = __builtin_amdgcn_mfma_f32_32x32x16_bf16(ka1, bq1, s, 0, 0, 0);

            uint4 w0, w1;
            if (allok) {
                float p0, p1, p2, p3;
                p0 = __expf(s[0] + lo16f(bw0.x)); p1 = __expf(s[1] + hi16f(bw0.x));
                p2 = __expf(s[2] + lo16f(bw0.y)); p3 = __expf(s[3] + hi16f(bw0.y));
                lsum += (p0 + p1) + (p2 + p3);
                w0.x = pk2(p0, p1); w0.y = pk2(p2, p3);
                p0 = __expf(s[4] + lo16f(bw1.x)); p1 = __expf(s[5] + hi16f(bw1.x));
                p2 = __expf(s[6] + lo16f(bw1.y)); p3 = __expf(s[7] + hi16f(bw1.y));
                lsum += (p0 + p1) + (p2 + p3);
                w0.z = pk2(p0, p1); w0.w = pk2(p2, p3);
                p0 = __expf(s[8] + lo16f(bw2.x)); p1 = __expf(s[9] + hi16f(bw2.x));
                p2 = __expf(s[10] + lo16f(bw2.y)); p3 = __expf(s[11] + hi16f(bw2.y));
                lsum += (p0 + p1) + (p2 + p3);
                w1.x = pk2(p0, p1); w1.y = pk2(p2, p3);
                p0 = __expf(s[12] + lo16f(bw3.x)); p1 = __expf(s[13] + hi16f(bw3.x));
                p2 = __expf(s[14] + lo16f(bw3.y)); p3 = __expf(s[15] + hi16f(bw3.y));
                lsum += (p0 + p1) + (p2 + p3);
                w1.z = pk2(p0, p1); w1.w = pk2(p2, p3);
            } else {
#pragma unroll
                for (int n = 0; n < 4; ++n) {
                    uint2 bw = (n == 0) ? bw0 : (n == 1) ? bw1 : (n == 2) ? bw2 : bw3;
                    f32x4 ma = *(const f32x4*)&pmsh[t * 32 + n * 8 + hi * 4];
                    float p0 = __expf(rowok ? s[4*n+0] + lo16f(bw.x) + ((ma[0] > 0.5f) ? 0.f : -1e9f) : 0.0f);
                    float p1 = __expf(rowok ? s[4*n+1] + hi16f(bw.x) + ((ma[1] > 0.5f) ? 0.f : -1e9f) : 0.0f);
                    float p2 = __expf(rowok ? s[4*n+2] + lo16f(bw.y) + ((ma[2] > 0.5f) ? 0.f : -1e9f) : 0.0f);
                    float p3 = __expf(rowok ? s[4*n+3] + hi16f(bw.y) + ((ma[3] > 0.5f) ? 0.f : -1e9f) : 0.0f);
                    lsum += (p0 + p1) + (p2 + p3);
                    unsigned wa = pk2(p0, p1), wb = pk2(p2, p3);
                    if (n == 0) { w0.x = wa; w0.y = wb; }
                    else if (n == 1) { w0.z = wa; w0.w = wb; }
                    else if (n == 2) { w1.x = wa; w1.y = wb; }
                    else { w1.z = wa; w1.w = wb; }
                }
            }
            short8v pb0 = *(short8v*)&w0;
            short8v pb1 = *(short8v*)&w1;

            short8v va0 = *(const short8v*)&VTsh[l31][t * 32 + hi * 8];
            short8v va1 = *(const short8v*)&VTsh[l31][t * 32 + 16 + hi * 8];
            oacc = __builtin_amdgcn_mfma_f32_32x32x16_bf16(va0, pb0, oacc, 0, 0, 0);
            oacc = __builtin_amdgcn_mfma_f32_32x32x16_bf16(va1, pb1, oacc, 0, 0, 0);
        }

        lsum += __shfl_xor(lsum, 32);
        const float linv = 1.0f / lsum;

        const long grow = hbase + (long)ql * 32;
        const long orow = (long)(i * 256 + ql) * 128 + h * 32;
#pragma unroll
        for (int n = 0; n < 4; ++n) {
            int dbase = n * 8 + hi * 4;
            float4 g4 = *(const float4*)(g_ws + grow + dbase);
            float v0 = oacc[4 * n + 0] * linv * g4.x;
            float v1 = oacc[4 * n + 1] * linv * g4.y;
            float v2 = oacc[4 * n + 2] * linv * g4.z;
            float v3 = oacc[4 * n + 3] * linv * g4.w;
            short h0 = f2bf(v0), h1 = f2bf(v1), h2 = f2bf(v2), h3 = f2bf(v3);
            short4 sh = {h0, h1, h2, h3};
            short4 sl = {f2bf(v0 - bf2f(h0)), f2bf(v1 - bf2f(h1)),
                         f2bf(v2 - bf2f(h2)), f2bf(v3 - bf2f(h3))};
            *(short4*)(ohi + orow + dbase) = sh;
            *(short4*)(olo + orow + dbase) = sl;
        }
    }
}

// ---------------------------------------------------------------------------
// KC: out = o @ Wo^T + bo. o pre-split hi/lo bf16 -> pure loads+MFMA.
// ---------------------------------------------------------------------------
__global__ __launch_bounds__(512, 4) void k_outproj(
    const unsigned short* __restrict__ ohi, const unsigned short* __restrict__ olo,
    const unsigned short* __restrict__ wohi, const unsigned short* __restrict__ wolo,
    const float* __restrict__ bo, float* __restrict__ out)
{
    const int tid  = threadIdx.x;
    const int lane = tid & 63;
    const int wave = tid >> 6;
    const int l15  = lane & 15;
    const int g    = lane >> 4;
    const int wr   = wave >> 2;
    const int wc   = wave & 3;
    const long p0  = (long)blockIdx.x * 128;

    f32x4 acc[4][2];
#pragma unroll
    for (int rt = 0; rt < 4; ++rt) {
        acc[rt][0] = (f32x4){0.f, 0.f, 0.f, 0.f};
        acc[rt][1] = (f32x4){0.f, 0.f, 0.f, 0.f};
    }

#pragma unroll
    for (int ks = 0; ks < 4; ++ks) {
        const int wof = ks * 32 + g * 8;
        short8v bh0 = *(const short8v*)(wohi + (wc * 32 + l15) * 128 + wof);
        short8v bh1 = *(const short8v*)(wohi + (wc * 32 + 16 + l15) * 128 + wof);
        short8v bl0 = *(const short8v*)(wolo + (wc * 32 + l15) * 128 + wof);
        short8v bl1 = *(const short8v*)(wolo + (wc * 32 + 16 + l15) * 128 + wof);
#pragma unroll
        for (int rt = 0; rt < 4; ++rt) {
            long aoff = (p0 + wr * 64 + rt * 16 + l15) * 128 + ks * 32 + g * 8;
            short8v ah = *(const short8v*)(ohi + aoff);
            short8v al = *(const short8v*)(olo + aoff);
            acc[rt][0] = __builtin_amdgcn_mfma_f32_16x16x32_bf16(ah, bh0, acc[rt][0], 0, 0, 0);
            acc[rt][0] = __builtin_amdgcn_mfma_f32_16x16x32_bf16(ah, bl0, acc[rt][0], 0, 0, 0);
            acc[rt][0] = __builtin_amdgcn_mfma_f32_16x16x32_bf16(al, bh0, acc[rt][0], 0, 0, 0);
            acc[rt][1] = __builtin_amdgcn_mfma_f32_16x16x32_bf16(ah, bh1, acc[rt][1], 0, 0, 0);
            acc[rt][1] = __builtin_amdgcn_mfma_f32_16x16x32_bf16(ah, bl1, acc[rt][1], 0, 0, 0);
            acc[rt][1] = __builtin_amdgcn_mfma_f32_16x16x32_bf16(al, bh1, acc[rt][1], 0, 0, 0);
        }
    }

#pragma unroll
    for (int ct = 0; ct < 2; ++ct) {
        float bv = bo[wc * 32 + ct * 16 + l15];
#pragma unroll
        for (int rt = 0; rt < 4; ++rt)
#pragma unroll
            for (int r = 0; r < 4; ++r)
                out[(p0 + wr * 64 + rt * 16 + g * 4 + r) * 128 +
                    wc * 32 + ct * 16 + l15] = acc[rt][ct][r] + bv;
    }
}

// ---------------------------------------------------------------------------
extern "C" void kernel_launch(void* const* d_in, const int* in_sizes, int n_in,
                              void* d_out, int out_size, void* d_ws, size_t ws_size,
                              hipStream_t stream) {
    const float* z   = (const float*)d_in[0];
    const float* pm  = (const float*)d_in[1];
    const float* lnw = (const float*)d_in[2];
    const float* lnb = (const float*)d_in[3];
    const float* Wq  = (const float*)d_in[4];
    const float* Wk  = (const float*)d_in[5];
    const float* Wv  = (const float*)d_in[6];
    const float* Wb  = (const float*)d_in[7];
    const float* Wg  = (const float*)d_in[8];
    const float* bg  = (const float*)d_in[9];
    const float* Wo  = (const float*)d_in[10];
    const float* bo  = (const float*)d_in[11];
    float* out = (float*)d_out;

    unsigned short* wsS  = (unsigned short*)d_ws;
    unsigned short* wbf  = wsS;                   // 65536
    unsigned short* wbbf = wsS + 65536;           // 512
    unsigned short* wohi = wsS + 66048;           // 16384
    unsigned short* wolo = wsS + 82432;           // 16384
    unsigned short* bbf  = wsS + 98816;           // 262144 bf16 [4][256][256]
    unsigned short* qb   = wsS + 360960;          // 8388608 bf16 [4][65536][32]
    unsigned short* kb   = qb + 8388608;
    unsigned short* vtb  = kb + 8388608;          // [4][256][32][256] (perm keys)
    unsigned short* ohiw = vtb + 8388608;         // 8388608 bf16 [65536][128]
    unsigned short* olow = ohiw + 8388608;        // 8388608
    float* gws = (float*)(olow + 8388608);        // 8388608 fp32 [4][65536][32]

    k_wprep<<<322, 256, 0, stream>>>(Wq, Wk, Wv, Wg, Wb, Wo, wbf, wbbf, wohi, wolo);
    k_lnproj<<<512, 512, 0, stream>>>(z, lnw, lnb, wbf, wbbf, bg, qb, kb, vtb, gws, bbf);
    k_attn_mfma<<<1024, 256, 0, stream>>>(qb, kb, vtb, gws, bbf, pm, ohiw, olow);
    k_outproj<<<512, 512, 0, stream>>>(ohiw, olow, wohi, wolo, bo, out);
}

// Round 11
// 104.128 us; speedup vs baseline: 3.0987x; 1.1645x over previous
//
#include <hip/hip_runtime.h>
#include <hip/hip_bf16.h>

#define ATT_SCALE 0.17677669529663687f   // 1/sqrt(32)
#define LOG2E     1.4426950408889634f

typedef __attribute__((ext_vector_type(8))) short short8v;
typedef __attribute__((ext_vector_type(4))) float f32x4;
typedef __attribute__((ext_vector_type(16))) float f32x16;

__device__ __forceinline__ short f2bf(float f) {
    unsigned u = __builtin_bit_cast(unsigned, f);
    u = u + 0x7fffu + ((u >> 16) & 1u);   // RNE
    return (short)(u >> 16);
}
__device__ __forceinline__ float bf2f(short s) {
    unsigned u = ((unsigned)(unsigned short)s) << 16;
    return __builtin_bit_cast(float, u);
}
__device__ __forceinline__ unsigned pk2(float lo, float hi) {
    return (unsigned)(unsigned short)f2bf(lo) |
           ((unsigned)(unsigned short)f2bf(hi) << 16);
}
__device__ __forceinline__ float lo16f(unsigned w) {
    return __builtin_bit_cast(float, w << 16);
}
__device__ __forceinline__ float hi16f(unsigned w) {
    return __builtin_bit_cast(float, w & 0xffff0000u);
}
__device__ __forceinline__ float exp2i(float x) {   // 2^x, single v_exp_f32
    float r;
    asm("v_exp_f32 %0, %1" : "=v"(r) : "v"(x));
    return r;
}
__device__ __forceinline__ unsigned short f2h(float f) {
    _Float16 h = (_Float16)f;
    return __builtin_bit_cast(unsigned short, h);
}
__device__ __forceinline__ float h2f(unsigned short u) {
    return (float)__builtin_bit_cast(_Float16, u);
}

// ---------------------------------------------------------------------------
// K0: one-time weight conversion. wbf = bf16{Wq*scale*log2e, Wk, Wv, Wg};
// wbbf = bf16 Wb; Wo -> hi/lo bf16 split.
// ---------------------------------------------------------------------------
__global__ __launch_bounds__(256) void k_wprep(
    const float* __restrict__ Wq, const float* __restrict__ Wk,
    const float* __restrict__ Wv, const float* __restrict__ Wg,
    const float* __restrict__ Wb, const float* __restrict__ Wo,
    unsigned short* __restrict__ wbf, unsigned short* __restrict__ wbbf,
    unsigned short* __restrict__ wohi, unsigned short* __restrict__ wolo)
{
    int idx = blockIdx.x * 256 + threadIdx.x;
    if (idx < 65536) {
        int m = idx >> 14, e = idx & 16383;
        float v;
        if (m == 0)      v = Wq[e] * (ATT_SCALE * LOG2E);
        else if (m == 1) v = Wk[e];
        else if (m == 2) v = Wv[e];
        else             v = Wg[e];
        wbf[idx] = (unsigned short)f2bf(v);
    } else if (idx < 66048) {
        int e = idx - 65536;
        wbbf[e] = (unsigned short)f2bf(Wb[e]);
    } else if (idx < 82432) {
        int e = idx - 66048;
        float w = Wo[e];
        short hv = f2bf(w);
        wohi[e] = (unsigned short)hv;
        wolo[e] = (unsigned short)f2bf(w - bf2f(hv));
    }
}

// ---------------------------------------------------------------------------
// KA: LN + projections + bias. 512 threads = 8 waves, block = 128 positions.
// q/k bf16 head-major [h][pos][32]; V bf16 TRANSPOSED + key-bit-2<->3-swapped.
// g fp16 head-major. bias bf16 (pre-scaled by log2e) natural [h][j][k].
// ---------------------------------------------------------------------------
__global__ __launch_bounds__(512, 4) void k_lnproj(
    const float* __restrict__ z, const float* __restrict__ lnw,
    const float* __restrict__ lnb,
    const unsigned short* __restrict__ wbf, const unsigned short* __restrict__ wbbf,
    const float* __restrict__ bg,
    unsigned short* __restrict__ q_o, unsigned short* __restrict__ k_o,
    unsigned short* __restrict__ vt_o, unsigned short* __restrict__ g_o,
    unsigned short* __restrict__ bbf)
{
    __shared__ __align__(16) short zn[128][136];
    __shared__ __align__(16) short wstg[8][32][40];

    const int tid  = threadIdx.x;
    const int lane = tid & 63;
    const int wave = tid >> 6;
    const int l15  = lane & 15;
    const int g    = lane >> 4;
    const int wr   = wave >> 2;
    const int wc   = wave & 3;
    const long p0  = (long)blockIdx.x * 128;
    const int xq   = (int)(p0 >> 8);
    const int y0   = (int)(p0 & 255);

    // ---- LN ----
    {
        const int r = tid >> 2, q4 = tid & 3;
        const float* zrow = z + (p0 + r) * 128 + q4 * 32;
        float4 xv[8];
        float s1 = 0.f, s2 = 0.f;
#pragma unroll
        for (int m = 0; m < 8; ++m) {
            xv[m] = *(const float4*)(zrow + m * 4);
            s1 += xv[m].x + xv[m].y + xv[m].z + xv[m].w;
            s2 += xv[m].x * xv[m].x + xv[m].y * xv[m].y +
                  xv[m].z * xv[m].z + xv[m].w * xv[m].w;
        }
        s1 += __shfl_xor(s1, 1); s2 += __shfl_xor(s2, 1);
        s1 += __shfl_xor(s1, 2); s2 += __shfl_xor(s2, 2);
        float mu  = s1 * 0.0078125f;
        float inv = rsqrtf(s2 * 0.0078125f - mu * mu + 1e-5f);
#pragma unroll
        for (int mm = 0; mm < 4; ++mm) {
            float4 a = xv[2 * mm], b = xv[2 * mm + 1];
            const float* wp = lnw + q4 * 32 + mm * 8;
            const float* bp = lnb + q4 * 32 + mm * 8;
            float4 w0 = *(const float4*)wp, w1 = *(const float4*)(wp + 4);
            float4 b0 = *(const float4*)bp, b1 = *(const float4*)(bp + 4);
            uint4 uu;
            uu.x = pk2((a.x - mu) * inv * w0.x + b0.x, (a.y - mu) * inv * w0.y + b0.y);
            uu.y = pk2((a.z - mu) * inv * w0.z + b0.z, (a.w - mu) * inv * w0.w + b0.w);
            uu.z = pk2((b.x - mu) * inv * w1.x + b1.x, (b.y - mu) * inv * w1.y + b1.y);
            uu.w = pk2((b.z - mu) * inv * w1.z + b1.z, (b.w - mu) * inv * w1.w + b1.w);
            *(uint4*)&zn[r][q4 * 32 + mm * 8] = uu;
        }
    }
    __syncthreads();

    // ---- pair bias (bf16 out, pre-scaled by log2e) ----
    if (wc == 0) {
        const unsigned short* wbp = wbbf + (l15 & 3) * 128;
        short8v wb[4];
#pragma unroll
        for (int ks = 0; ks < 4; ++ks)
            wb[ks] = *(const short8v*)(wbp + ks * 32 + g * 8);
        f32x4 bacc[4];
#pragma unroll
        for (int rt = 0; rt < 4; ++rt) bacc[rt] = (f32x4){0.f, 0.f, 0.f, 0.f};
#pragma unroll
        for (int ks = 0; ks < 4; ++ks)
#pragma unroll
            for (int rt = 0; rt < 4; ++rt) {
                short8v a = *(const short8v*)&zn[wr * 64 + rt * 16 + l15][ks * 32 + g * 8];
                bacc[rt] = __builtin_amdgcn_mfma_f32_16x16x32_bf16(a, wb[ks], bacc[rt], 0, 0, 0);
            }
        if (l15 < 4) {
#pragma unroll
            for (int rt = 0; rt < 4; ++rt) {
                uint2 w;
                w.x = pk2(bacc[rt][0] * LOG2E, bacc[rt][1] * LOG2E);
                w.y = pk2(bacc[rt][2] * LOG2E, bacc[rt][3] * LOG2E);
                *(uint2*)(bbf + (long)l15 * 65536 + xq * 256 + y0 +
                          wr * 64 + rt * 16 + g * 4) = w;
            }
        }
    }

    // ---- 4 projection matrices ----
    for (int wsel = 0; wsel < 4; ++wsel) {
        const unsigned short* __restrict__ W = wbf + wsel * 16384;
        f32x4 acc[4][2];
#pragma unroll
        for (int rt = 0; rt < 4; ++rt) {
            acc[rt][0] = (f32x4){0.f, 0.f, 0.f, 0.f};
            acc[rt][1] = (f32x4){0.f, 0.f, 0.f, 0.f};
        }
#pragma unroll
        for (int ks = 0; ks < 4; ++ks) {
            short8v b0 = *(const short8v*)(W + (wc * 32 + l15) * 128 + ks * 32 + g * 8);
            short8v b1 = *(const short8v*)(W + (wc * 32 + 16 + l15) * 128 + ks * 32 + g * 8);
#pragma unroll
            for (int rt = 0; rt < 4; ++rt) {
                short8v a = *(const short8v*)&zn[wr * 64 + rt * 16 + l15][ks * 32 + g * 8];
                acc[rt][0] = __builtin_amdgcn_mfma_f32_16x16x32_bf16(a, b0, acc[rt][0], 0, 0, 0);
                acc[rt][1] = __builtin_amdgcn_mfma_f32_16x16x32_bf16(a, b1, acc[rt][1], 0, 0, 0);
            }
        }

        if (wsel == 3) {
            // sigmoid gate, fp16 head-major [h][pos][32]
#pragma unroll
            for (int ct = 0; ct < 2; ++ct) {
                float bgc = bg[wc * 32 + ct * 16 + l15];
#pragma unroll
                for (int rt = 0; rt < 4; ++rt)
#pragma unroll
                    for (int r = 0; r < 4; ++r) {
                        float val = acc[rt][ct][r] + bgc;
                        g_o[((long)wc * 65536 + p0 + wr * 64 + rt * 16 + g * 4 + r) * 32 +
                            ct * 16 + l15] = f2h(1.0f / (1.0f + __expf(-val)));
                    }
            }
        } else if (wsel == 2) {
            // V: stage transposed, copy out with key-bit-2<->3 swap (per 32 keys)
#pragma unroll
            for (int pair = 0; pair < 2; ++pair) {
#pragma unroll
                for (int rt2 = 0; rt2 < 2; ++rt2)
#pragma unroll
                    for (int ct = 0; ct < 2; ++ct)
#pragma unroll
                        for (int r = 0; r < 4; ++r)
                            wstg[wave][ct * 16 + l15][rt2 * 16 + g * 4 + r] =
                                f2bf(acc[pair * 2 + rt2][ct][r]);
#pragma unroll
                for (int e = 0; e < 4; ++e) {
                    int idx = e * 64 + lane;
                    int d = idx >> 3, k4 = idx & 7;
                    int k4p = ((k4 & 1) << 1) | ((k4 >> 1) & 1) | (k4 & 4);
                    short4 sv = *(const short4*)&wstg[wave][d][k4 * 4];
                    *(short4*)(vt_o + (((long)wc * 256 + xq) * 32 + d) * 256 +
                               y0 + wr * 64 + pair * 32 + k4p * 4) = sv;
                }
            }
        } else {
            unsigned short* __restrict__ O = (wsel == 0) ? q_o : k_o;
#pragma unroll
            for (int pair = 0; pair < 2; ++pair) {
#pragma unroll
                for (int rt2 = 0; rt2 < 2; ++rt2)
#pragma unroll
                    for (int ct = 0; ct < 2; ++ct)
#pragma unroll
                        for (int r = 0; r < 4; ++r)
                            wstg[wave][rt2 * 16 + g * 4 + r][ct * 16 + l15] =
                                f2bf(acc[pair * 2 + rt2][ct][r]);
#pragma unroll
                for (int ps = 0; ps < 2; ++ps) {
                    int idx = ps * 64 + lane;
                    int lr = idx >> 2, ch = (idx & 3) * 8;
                    short8v vv = *(const short8v*)&wstg[wave][lr][ch];
                    *(short8v*)(O + ((long)wc * 65536 + p0 + wr * 64 + pair * 32 + lr) * 32 + ch) = vv;
                }
            }
        }
    }
}

// ---------------------------------------------------------------------------
// KB: attention, 32x32 MFMA, softmax fully in registers. q pre-scaled by
// scale*log2e, bias pre-scaled by log2e -> p = v_exp_f32(s+b) directly.
// o written as SINGLE bf16 (v is bf16 already; same error class).
// launch_bounds(256,2): do not tighten (R9: forced cap -> 450MB scratch).
// ---------------------------------------------------------------------------
__global__ __launch_bounds__(256, 2) void k_attn_mfma(
    const unsigned short* __restrict__ q_ws, const unsigned short* __restrict__ k_ws,
    const unsigned short* __restrict__ vt_ws, const unsigned short* __restrict__ g_ws,
    const unsigned short* __restrict__ bbf, const float* __restrict__ pm,
    unsigned short* __restrict__ ob)
{
    __shared__ __align__(16) short Ksh[256][40];    // 20.5 KB
    __shared__ __align__(16) short VTsh[32][264];   // 16.9 KB
    __shared__ float pmsh[256];

    const int tid  = threadIdx.x;
    const int lane = tid & 63;
    const int wave = tid >> 6;
    const int l31  = lane & 31;
    const int hi   = lane >> 5;
    const int h = blockIdx.x & 3;
    const int i = blockIdx.x >> 2;
    const long hbase  = ((long)h * 65536 + (long)i * 256) * 32;
    const long vtbase = ((long)h * 256 + i) * 8192;

    pmsh[tid] = pm[i * 256 + tid];
#pragma unroll
    for (int pass = 0; pass < 4; ++pass) {
        int idx = pass * 256 + tid;          // 0..1023
        *(short8v*)&Ksh[idx >> 2][(idx & 3) * 8] =
            *(const short8v*)(k_ws + hbase + idx * 8);
        *(short8v*)&VTsh[idx >> 5][(idx & 31) * 8] =
            *(const short8v*)(vt_ws + vtbase + idx * 8);
    }
    __syncthreads();

    bool ok4 = true;
#pragma unroll
    for (int e = 0; e < 4; ++e) ok4 = ok4 && (pmsh[lane * 4 + e] > 0.5f);
    const bool allok = __all(ok4);

    const f32x16 zero16 = {0.f,0.f,0.f,0.f,0.f,0.f,0.f,0.f,
                           0.f,0.f,0.f,0.f,0.f,0.f,0.f,0.f};

    for (int qi = 0; qi < 2; ++qi) {
        const int qb = wave * 2 + qi;
        const int ql = qb * 32 + l31;

        short8v bq0 = *(const short8v*)(q_ws + hbase + (long)ql * 32 + hi * 8);
        short8v bq1 = *(const short8v*)(q_ws + hbase + (long)ql * 32 + 16 + hi * 8);
        const bool rowok = pmsh[ql] > 0.5f;
        const unsigned short* bp_base = bbf + ((long)h << 16) + (long)ql * 256 + hi * 4;

        f32x16 oacc = zero16;
        float ls0 = 0.f, ls1 = 0.f;

#pragma unroll
        for (int t = 0; t < 8; ++t) {
            uint2 bw0 = *(const uint2*)(bp_base + t * 32);
            uint2 bw1 = *(const uint2*)(bp_base + t * 32 + 8);
            uint2 bw2 = *(const uint2*)(bp_base + t * 32 + 16);
            uint2 bw3 = *(const uint2*)(bp_base + t * 32 + 24);

            short8v ka0 = *(const short8v*)&Ksh[t * 32 + l31][hi * 8];
            short8v ka1 = *(const short8v*)&Ksh[t * 32 + l31][16 + hi * 8];
            __builtin_amdgcn_s_setprio(1);
            f32x16 s = __builtin_amdgcn_mfma_f32_32x32x16_bf16(ka0, bq0, zero16, 0, 0, 0);
            s = __builtin_amdgcn_mfma_f32_32x32x16_bf16(ka1, bq1, s, 0, 0, 0);
            __builtin_amdgcn_s_setprio(0);

            uint4 w0, w1;
            if (allok) {
                float p0, p1, p2, p3;
                p0 = exp2i(s[0] + lo16f(bw0.x)); p1 = exp2i(s[1] + hi16f(bw0.x));
                p2 = exp2i(s[2] + lo16f(bw0.y)); p3 = exp2i(s[3] + hi16f(bw0.y));
                ls0 += (p0 + p1) + (p2 + p3);
                w0.x = pk2(p0, p1); w0.y = pk2(p2, p3);
                p0 = exp2i(s[4] + lo16f(bw1.x)); p1 = exp2i(s[5] + hi16f(bw1.x));
                p2 = exp2i(s[6] + lo16f(bw1.y)); p3 = exp2i(s[7] + hi16f(bw1.y));
                ls1 += (p0 + p1) + (p2 + p3);
                w0.z = pk2(p0, p1); w0.w = pk2(p2, p3);
                p0 = exp2i(s[8] + lo16f(bw2.x)); p1 = exp2i(s[9] + hi16f(bw2.x));
                p2 = exp2i(s[10] + lo16f(bw2.y)); p3 = exp2i(s[11] + hi16f(bw2.y));
                ls0 += (p0 + p1) + (p2 + p3);
                w1.x = pk2(p0, p1); w1.y = pk2(p2, p3);
                p0 = exp2i(s[12] + lo16f(bw3.x)); p1 = exp2i(s[13] + hi16f(bw3.x));
                p2 = exp2i(s[14] + lo16f(bw3.y)); p3 = exp2i(s[15] + hi16f(bw3.y));
                ls1 += (p0 + p1) + (p2 + p3);
                w1.z = pk2(p0, p1); w1.w = pk2(p2, p3);
            } else {
#pragma unroll
                for (int n = 0; n < 4; ++n) {
                    uint2 bw = (n == 0) ? bw0 : (n == 1) ? bw1 : (n == 2) ? bw2 : bw3;
                    f32x4 ma = *(const f32x4*)&pmsh[t * 32 + n * 8 + hi * 4];
                    float p0 = exp2i(rowok ? s[4*n+0] + lo16f(bw.x) + ((ma[0] > 0.5f) ? 0.f : -1e9f) : 0.0f);
                    float p1 = exp2i(rowok ? s[4*n+1] + hi16f(bw.x) + ((ma[1] > 0.5f) ? 0.f : -1e9f) : 0.0f);
                    float p2 = exp2i(rowok ? s[4*n+2] + lo16f(bw.y) + ((ma[2] > 0.5f) ? 0.f : -1e9f) : 0.0f);
                    float p3 = exp2i(rowok ? s[4*n+3] + hi16f(bw.y) + ((ma[3] > 0.5f) ? 0.f : -1e9f) : 0.0f);
                    ls0 += (p0 + p1) + (p2 + p3);
                    unsigned wa = pk2(p0, p1), wb = pk2(p2, p3);
                    if (n == 0) { w0.x = wa; w0.y = wb; }
                    else if (n == 1) { w0.z = wa; w0.w = wb; }
                    else if (n == 2) { w1.x = wa; w1.y = wb; }
                    else { w1.z = wa; w1.w = wb; }
                }
            }
            short8v pb0 = *(short8v*)&w0;
            short8v pb1 = *(short8v*)&w1;

            short8v va0 = *(const short8v*)&VTsh[l31][t * 32 + hi * 8];
            short8v va1 = *(const short8v*)&VTsh[l31][t * 32 + 16 + hi * 8];
            __builtin_amdgcn_s_setprio(1);
            oacc = __builtin_amdgcn_mfma_f32_32x32x16_bf16(va0, pb0, oacc, 0, 0, 0);
            oacc = __builtin_amdgcn_mfma_f32_32x32x16_bf16(va1, pb1, oacc, 0, 0, 0);
            __builtin_amdgcn_s_setprio(0);
        }

        float lsum = ls0 + ls1;
        lsum += __shfl_xor(lsum, 32);
        const float linv = 1.0f / lsum;

        const long grow = hbase + (long)ql * 32;
        const long orow = (long)(i * 256 + ql) * 128 + h * 32;
#pragma unroll
        for (int n = 0; n < 4; ++n) {
            int dbase = n * 8 + hi * 4;
            ushort4 gu = *(const ushort4*)(g_ws + grow + dbase);
            float v0 = oacc[4 * n + 0] * linv * h2f(gu.x);
            float v1 = oacc[4 * n + 1] * linv * h2f(gu.y);
            float v2 = oacc[4 * n + 2] * linv * h2f(gu.z);
            float v3 = oacc[4 * n + 3] * linv * h2f(gu.w);
            short4 sh = {f2bf(v0), f2bf(v1), f2bf(v2), f2bf(v3)};
            *(short4*)(ob + orow + dbase) = sh;
        }
    }
}

// ---------------------------------------------------------------------------
// KC: out = o @ Wo^T + bo. o single bf16, Wo hi/lo -> 2 MFMAs per fragment.
// ---------------------------------------------------------------------------
__global__ __launch_bounds__(512, 4) void k_outproj(
    const unsigned short* __restrict__ ob,
    const unsigned short* __restrict__ wohi, const unsigned short* __restrict__ wolo,
    const float* __restrict__ bo, float* __restrict__ out)
{
    const int tid  = threadIdx.x;
    const int lane = tid & 63;
    const int wave = tid >> 6;
    const int l15  = lane & 15;
    const int g    = lane >> 4;
    const int wr   = wave >> 2;
    const int wc   = wave & 3;
    const long p0  = (long)blockIdx.x * 128;

    f32x4 acc[4][2];
#pragma unroll
    for (int rt = 0; rt < 4; ++rt) {
        acc[rt][0] = (f32x4){0.f, 0.f, 0.f, 0.f};
        acc[rt][1] = (f32x4){0.f, 0.f, 0.f, 0.f};
    }

#pragma unroll
    for (int ks = 0; ks < 4; ++ks) {
        const int wof = ks * 32 + g * 8;
        short8v bh0 = *(const short8v*)(wohi + (wc * 32 + l15) * 128 + wof);
        short8v bh1 = *(const short8v*)(wohi + (wc * 32 + 16 + l15) * 128 + wof);
        short8v bl0 = *(const short8v*)(wolo + (wc * 32 + l15) * 128 + wof);
        short8v bl1 = *(const short8v*)(wolo + (wc * 32 + 16 + l15) * 128 + wof);
#pragma unroll
        for (int rt = 0; rt < 4; ++rt) {
            long aoff = (p0 + wr * 64 + rt * 16 + l15) * 128 + ks * 32 + g * 8;
            short8v ah = *(const short8v*)(ob + aoff);
            acc[rt][0] = __builtin_amdgcn_mfma_f32_16x16x32_bf16(ah, bh0, acc[rt][0], 0, 0, 0);
            acc[rt][0] = __builtin_amdgcn_mfma_f32_16x16x32_bf16(ah, bl0, acc[rt][0], 0, 0, 0);
            acc[rt][1] = __builtin_amdgcn_mfma_f32_16x16x32_bf16(ah, bh1, acc[rt][1], 0, 0, 0);
            acc[rt][1] = __builtin_amdgcn_mfma_f32_16x16x32_bf16(ah, bl1, acc[rt][1], 0, 0, 0);
        }
    }

#pragma unroll
    for (int ct = 0; ct < 2; ++ct) {
        float bv = bo[wc * 32 + ct * 16 + l15];
#pragma unroll
        for (int rt = 0; rt < 4; ++rt)
#pragma unroll
            for (int r = 0; r < 4; ++r)
                out[(p0 + wr * 64 + rt * 16 + g * 4 + r) * 128 +
                    wc * 32 + ct * 16 + l15] = acc[rt][ct][r] + bv;
    }
}

// ---------------------------------------------------------------------------
extern "C" void kernel_launch(void* const* d_in, const int* in_sizes, int n_in,
                              void* d_out, int out_size, void* d_ws, size_t ws_size,
                              hipStream_t stream) {
    const float* z   = (const float*)d_in[0];
    const float* pm  = (const float*)d_in[1];
    const float* lnw = (const float*)d_in[2];
    const float* lnb = (const float*)d_in[3];
    const float* Wq  = (const float*)d_in[4];
    const float* Wk  = (const float*)d_in[5];
    const float* Wv  = (const float*)d_in[6];
    const float* Wb  = (const float*)d_in[7];
    const float* Wg  = (const float*)d_in[8];
    const float* bg  = (const float*)d_in[9];
    const float* Wo  = (const float*)d_in[10];
    const float* bo  = (const float*)d_in[11];
    float* out = (float*)d_out;

    unsigned short* wsS  = (unsigned short*)d_ws;
    unsigned short* wbf  = wsS;                   // 65536
    unsigned short* wbbf = wsS + 65536;           // 512
    unsigned short* wohi = wsS + 66048;           // 16384
    unsigned short* wolo = wsS + 82432;           // 16384
    unsigned short* bbf  = wsS + 98816;           // 262144 bf16 [4][256][256]
    unsigned short* qb   = wsS + 360960;          // 8388608 bf16 [4][65536][32]
    unsigned short* kb   = qb + 8388608;
    unsigned short* vtb  = kb + 8388608;          // [4][256][32][256] (perm keys)
    unsigned short* obw  = vtb + 8388608;         // 8388608 bf16 [65536][128]
    unsigned short* ghw  = obw + 8388608;         // 8388608 fp16 [4][65536][32]

    k_wprep<<<322, 256, 0, stream>>>(Wq, Wk, Wv, Wg, Wb, Wo, wbf, wbbf, wohi, wolo);
    k_lnproj<<<512, 512, 0, stream>>>(z, lnw, lnb, wbf, wbbf, bg, qb, kb, vtb, ghw, bbf);
    k_attn_mfma<<<1024, 256, 0, stream>>>(qb, kb, vtb, ghw, bbf, pm, obw);
    k_outproj<<<512, 512, 0, stream>>>(obw, wohi, wolo, bo, out);
}

// Round 12
// 91.475 us; speedup vs baseline: 3.5273x; 1.1383x over previous
//
#include <hip/hip_runtime.h>
#include <hip/hip_bf16.h>

#define ATT_SCALE 0.17677669529663687f   // 1/sqrt(32)
#define LOG2E     1.4426950408889634f

typedef __attribute__((ext_vector_type(8))) short short8v;
typedef __attribute__((ext_vector_type(4))) float f32x4;
typedef __attribute__((ext_vector_type(16))) float f32x16;

__device__ __forceinline__ short f2bf(float f) {
    unsigned u = __builtin_bit_cast(unsigned, f);
    u = u + 0x7fffu + ((u >> 16) & 1u);   // RNE
    return (short)(u >> 16);
}
__device__ __forceinline__ float bf2f(short s) {
    unsigned u = ((unsigned)(unsigned short)s) << 16;
    return __builtin_bit_cast(float, u);
}
__device__ __forceinline__ unsigned pk2(float lo, float hi) {
    return (unsigned)(unsigned short)f2bf(lo) |
           ((unsigned)(unsigned short)f2bf(hi) << 16);
}
__device__ __forceinline__ float lo16f(unsigned w) {
    return __builtin_bit_cast(float, w << 16);
}
__device__ __forceinline__ float hi16f(unsigned w) {
    return __builtin_bit_cast(float, w & 0xffff0000u);
}
__device__ __forceinline__ float exp2i(float x) {   // 2^x, single v_exp_f32
    float r;
    asm("v_exp_f32 %0, %1" : "=v"(r) : "v"(x));
    return r;
}
__device__ __forceinline__ unsigned short f2h(float f) {
    _Float16 h = (_Float16)f;
    return __builtin_bit_cast(unsigned short, h);
}
__device__ __forceinline__ float h2f(unsigned short u) {
    return (float)__builtin_bit_cast(_Float16, u);
}

// ---------------------------------------------------------------------------
// K0: one-time weight conversion. wbf = bf16{Wq*scale*log2e, Wk, Wv, Wg};
// wbbf = bf16 Wb; Wo -> hi/lo bf16 split.
// ---------------------------------------------------------------------------
__global__ __launch_bounds__(256) void k_wprep(
    const float* __restrict__ Wq, const float* __restrict__ Wk,
    const float* __restrict__ Wv, const float* __restrict__ Wg,
    const float* __restrict__ Wb, const float* __restrict__ Wo,
    unsigned short* __restrict__ wbf, unsigned short* __restrict__ wbbf,
    unsigned short* __restrict__ wohi, unsigned short* __restrict__ wolo)
{
    int idx = blockIdx.x * 256 + threadIdx.x;
    if (idx < 65536) {
        int m = idx >> 14, e = idx & 16383;
        float v;
        if (m == 0)      v = Wq[e] * (ATT_SCALE * LOG2E);
        else if (m == 1) v = Wk[e];
        else if (m == 2) v = Wv[e];
        else             v = Wg[e];
        wbf[idx] = (unsigned short)f2bf(v);
    } else if (idx < 66048) {
        int e = idx - 65536;
        wbbf[e] = (unsigned short)f2bf(Wb[e]);
    } else if (idx < 82432) {
        int e = idx - 66048;
        float w = Wo[e];
        short hv = f2bf(w);
        wohi[e] = (unsigned short)hv;
        wolo[e] = (unsigned short)f2bf(w - bf2f(hv));
    }
}

// ---------------------------------------------------------------------------
// KA: LN + projections + bias. 512 threads = 8 waves, block = 128 positions.
// q/k bf16 head-major [h][pos][32]; V bf16 TRANSPOSED + key-bit-2<->3-swapped.
// g fp16 head-major. bias uint-packed TRANSPOSED bTP[h][key/2][query]
// (lo16 = key 2m, hi16 = key 2m+1; pre-scaled by log2e).
// ---------------------------------------------------------------------------
__global__ __launch_bounds__(512, 4) void k_lnproj(
    const float* __restrict__ z, const float* __restrict__ lnw,
    const float* __restrict__ lnb,
    const unsigned short* __restrict__ wbf, const unsigned short* __restrict__ wbbf,
    const float* __restrict__ bg,
    unsigned short* __restrict__ q_o, unsigned short* __restrict__ k_o,
    unsigned short* __restrict__ vt_o, unsigned short* __restrict__ g_o,
    unsigned* __restrict__ bTP)
{
    __shared__ __align__(16) short zn[128][136];
    __shared__ __align__(16) short wstg[8][32][40];

    const int tid  = threadIdx.x;
    const int lane = tid & 63;
    const int wave = tid >> 6;
    const int l15  = lane & 15;
    const int g    = lane >> 4;
    const int wr   = wave >> 2;
    const int wc   = wave & 3;
    const long p0  = (long)blockIdx.x * 128;
    const int xq   = (int)(p0 >> 8);
    const int y0   = (int)(p0 & 255);

    // ---- LN ----
    {
        const int r = tid >> 2, q4 = tid & 3;
        const float* zrow = z + (p0 + r) * 128 + q4 * 32;
        float4 xv[8];
        float s1 = 0.f, s2 = 0.f;
#pragma unroll
        for (int m = 0; m < 8; ++m) {
            xv[m] = *(const float4*)(zrow + m * 4);
            s1 += xv[m].x + xv[m].y + xv[m].z + xv[m].w;
            s2 += xv[m].x * xv[m].x + xv[m].y * xv[m].y +
                  xv[m].z * xv[m].z + xv[m].w * xv[m].w;
        }
        s1 += __shfl_xor(s1, 1); s2 += __shfl_xor(s2, 1);
        s1 += __shfl_xor(s1, 2); s2 += __shfl_xor(s2, 2);
        float mu  = s1 * 0.0078125f;
        float inv = rsqrtf(s2 * 0.0078125f - mu * mu + 1e-5f);
#pragma unroll
        for (int mm = 0; mm < 4; ++mm) {
            float4 a = xv[2 * mm], b = xv[2 * mm + 1];
            const float* wp = lnw + q4 * 32 + mm * 8;
            const float* bp = lnb + q4 * 32 + mm * 8;
            float4 w0 = *(const float4*)wp, w1 = *(const float4*)(wp + 4);
            float4 b0 = *(const float4*)bp, b1 = *(const float4*)(bp + 4);
            uint4 uu;
            uu.x = pk2((a.x - mu) * inv * w0.x + b0.x, (a.y - mu) * inv * w0.y + b0.y);
            uu.y = pk2((a.z - mu) * inv * w0.z + b0.z, (a.w - mu) * inv * w0.w + b0.w);
            uu.z = pk2((b.x - mu) * inv * w1.x + b1.x, (b.y - mu) * inv * w1.y + b1.y);
            uu.w = pk2((b.z - mu) * inv * w1.z + b1.z, (b.w - mu) * inv * w1.w + b1.w);
            *(uint4*)&zn[r][q4 * 32 + mm * 8] = uu;
        }
    }
    __syncthreads();

    // ---- pair bias: packed-transposed bTP[h][key/2][query], scaled log2e ----
    if (wc == 0) {
        const unsigned short* wbp = wbbf + (l15 & 3) * 128;
        short8v wb[4];
#pragma unroll
        for (int ks = 0; ks < 4; ++ks)
            wb[ks] = *(const short8v*)(wbp + ks * 32 + g * 8);
        f32x4 bacc[4];
#pragma unroll
        for (int rt = 0; rt < 4; ++rt) bacc[rt] = (f32x4){0.f, 0.f, 0.f, 0.f};
#pragma unroll
        for (int ks = 0; ks < 4; ++ks)
#pragma unroll
            for (int rt = 0; rt < 4; ++rt) {
                short8v a = *(const short8v*)&zn[wr * 64 + rt * 16 + l15][ks * 32 + g * 8];
                bacc[rt] = __builtin_amdgcn_mfma_f32_16x16x32_bf16(a, wb[ks], bacc[rt], 0, 0, 0);
            }
        if (l15 < 4) {
#pragma unroll
            for (int rt = 0; rt < 4; ++rt) {
                int kb = y0 + wr * 64 + rt * 16 + g * 4;   // even key base
                unsigned w0 = pk2(bacc[rt][0] * LOG2E, bacc[rt][1] * LOG2E);
                unsigned w1 = pk2(bacc[rt][2] * LOG2E, bacc[rt][3] * LOG2E);
                bTP[l15 * 32768 + (kb >> 1) * 256 + xq]       = w0;
                bTP[l15 * 32768 + ((kb >> 1) + 1) * 256 + xq] = w1;
            }
        }
    }

    // ---- 4 projection matrices ----
    for (int wsel = 0; wsel < 4; ++wsel) {
        const unsigned short* __restrict__ W = wbf + wsel * 16384;
        f32x4 acc[4][2];
#pragma unroll
        for (int rt = 0; rt < 4; ++rt) {
            acc[rt][0] = (f32x4){0.f, 0.f, 0.f, 0.f};
            acc[rt][1] = (f32x4){0.f, 0.f, 0.f, 0.f};
        }
#pragma unroll
        for (int ks = 0; ks < 4; ++ks) {
            short8v b0 = *(const short8v*)(W + (wc * 32 + l15) * 128 + ks * 32 + g * 8);
            short8v b1 = *(const short8v*)(W + (wc * 32 + 16 + l15) * 128 + ks * 32 + g * 8);
#pragma unroll
            for (int rt = 0; rt < 4; ++rt) {
                short8v a = *(const short8v*)&zn[wr * 64 + rt * 16 + l15][ks * 32 + g * 8];
                acc[rt][0] = __builtin_amdgcn_mfma_f32_16x16x32_bf16(a, b0, acc[rt][0], 0, 0, 0);
                acc[rt][1] = __builtin_amdgcn_mfma_f32_16x16x32_bf16(a, b1, acc[rt][1], 0, 0, 0);
            }
        }

        if (wsel == 3) {
            // sigmoid gate, fp16 head-major [h][pos][32]
#pragma unroll
            for (int ct = 0; ct < 2; ++ct) {
                float bgc = bg[wc * 32 + ct * 16 + l15];
#pragma unroll
                for (int rt = 0; rt < 4; ++rt)
#pragma unroll
                    for (int r = 0; r < 4; ++r) {
                        float val = acc[rt][ct][r] + bgc;
                        g_o[((long)wc * 65536 + p0 + wr * 64 + rt * 16 + g * 4 + r) * 32 +
                            ct * 16 + l15] = f2h(1.0f / (1.0f + __expf(-val)));
                    }
            }
        } else if (wsel == 2) {
            // V: stage transposed, copy out with key-bit-2<->3 swap (per 32 keys)
#pragma unroll
            for (int pair = 0; pair < 2; ++pair) {
#pragma unroll
                for (int rt2 = 0; rt2 < 2; ++rt2)
#pragma unroll
                    for (int ct = 0; ct < 2; ++ct)
#pragma unroll
                        for (int r = 0; r < 4; ++r)
                            wstg[wave][ct * 16 + l15][rt2 * 16 + g * 4 + r] =
                                f2bf(acc[pair * 2 + rt2][ct][r]);
#pragma unroll
                for (int e = 0; e < 4; ++e) {
                    int idx = e * 64 + lane;
                    int d = idx >> 3, k4 = idx & 7;
                    int k4p = ((k4 & 1) << 1) | ((k4 >> 1) & 1) | (k4 & 4);
                    short4 sv = *(const short4*)&wstg[wave][d][k4 * 4];
                    *(short4*)(vt_o + (((long)wc * 256 + xq) * 32 + d) * 256 +
                               y0 + wr * 64 + pair * 32 + k4p * 4) = sv;
                }
            }
        } else {
            unsigned short* __restrict__ O = (wsel == 0) ? q_o : k_o;
#pragma unroll
            for (int pair = 0; pair < 2; ++pair) {
#pragma unroll
                for (int rt2 = 0; rt2 < 2; ++rt2)
#pragma unroll
                    for (int ct = 0; ct < 2; ++ct)
#pragma unroll
                        for (int r = 0; r < 4; ++r)
                            wstg[wave][rt2 * 16 + g * 4 + r][ct * 16 + l15] =
                                f2bf(acc[pair * 2 + rt2][ct][r]);
#pragma unroll
                for (int ps = 0; ps < 2; ++ps) {
                    int idx = ps * 64 + lane;
                    int lr = idx >> 2, ch = (idx & 3) * 8;
                    short8v vv = *(const short8v*)&wstg[wave][lr][ch];
                    *(short8v*)(O + ((long)wc * 65536 + p0 + wr * 64 + pair * 32 + lr) * 32 + ch) = vv;
                }
            }
        }
    }
}

// ---------------------------------------------------------------------------
// KB: attention, 32x32 MFMA, in-register softmax, one-deep software pipeline:
// t+1's LDS fragments + bias uints prefetched during t's MFMA/exp work.
// Bias loads are lane-coalesced (bTP[h][key/2][query]).
// launch_bounds(256,2): do not tighten (R9: forced cap -> scratch blowup).
// ---------------------------------------------------------------------------
__global__ __launch_bounds__(256, 2) void k_attn_mfma(
    const unsigned short* __restrict__ q_ws, const unsigned short* __restrict__ k_ws,
    const unsigned short* __restrict__ vt_ws, const unsigned short* __restrict__ g_ws,
    const unsigned* __restrict__ bTP, const float* __restrict__ pm,
    unsigned short* __restrict__ ob)
{
    __shared__ __align__(16) short Ksh[256][40];    // 20.5 KB
    __shared__ __align__(16) short VTsh[32][264];   // 16.9 KB
    __shared__ float pmsh[256];

    const int tid  = threadIdx.x;
    const int lane = tid & 63;
    const int wave = tid >> 6;
    const int l31  = lane & 31;
    const int hi   = lane >> 5;
    const int h = blockIdx.x & 3;
    const int i = blockIdx.x >> 2;
    const long hbase  = ((long)h * 65536 + (long)i * 256) * 32;
    const long vtbase = ((long)h * 256 + i) * 8192;

    pmsh[tid] = pm[i * 256 + tid];
#pragma unroll
    for (int pass = 0; pass < 4; ++pass) {
        int idx = pass * 256 + tid;          // 0..1023
        *(short8v*)&Ksh[idx >> 2][(idx & 3) * 8] =
            *(const short8v*)(k_ws + hbase + idx * 8);
        *(short8v*)&VTsh[idx >> 5][(idx & 31) * 8] =
            *(const short8v*)(vt_ws + vtbase + idx * 8);
    }
    __syncthreads();

    bool ok4 = true;
#pragma unroll
    for (int e = 0; e < 4; ++e) ok4 = ok4 && (pmsh[lane * 4 + e] > 0.5f);
    const bool allok = __all(ok4);

    const f32x16 zero16 = {0.f,0.f,0.f,0.f,0.f,0.f,0.f,0.f,
                           0.f,0.f,0.f,0.f,0.f,0.f,0.f,0.f};

    for (int qi = 0; qi < 2; ++qi) {
        const int qb = wave * 2 + qi;
        const int ql = qb * 32 + l31;

        short8v bq0 = *(const short8v*)(q_ws + hbase + (long)ql * 32 + hi * 8);
        short8v bq1 = *(const short8v*)(q_ws + hbase + (long)ql * 32 + 16 + hi * 8);
        const bool rowok = pmsh[ql] > 0.5f;
        const unsigned* btp = bTP + h * 32768 + ql;   // [key/2]*256 stride

        // prefetch epilogue gate values now (independent)
        const long grow = hbase + (long)ql * 32;
        ushort4 gu[4];
#pragma unroll
        for (int n = 0; n < 4; ++n)
            gu[n] = *(const ushort4*)(g_ws + grow + n * 8 + hi * 4);

        f32x16 oacc = zero16;
        float ls0 = 0.f, ls1 = 0.f;

        // ---- pipeline stage 0 ----
        short8v ka0 = *(const short8v*)&Ksh[l31][hi * 8];
        short8v ka1 = *(const short8v*)&Ksh[l31][16 + hi * 8];
        short8v va0 = *(const short8v*)&VTsh[l31][hi * 8];
        short8v va1 = *(const short8v*)&VTsh[l31][16 + hi * 8];
        unsigned bb[8];
#pragma unroll
        for (int n = 0; n < 4; ++n) {
            int m = (n * 8 + hi * 4) >> 1;
            bb[2 * n]     = btp[m * 256];
            bb[2 * n + 1] = btp[(m + 1) * 256];
        }

#pragma unroll
        for (int t = 0; t < 8; ++t) {
            // ---- issue next-stage loads first (overlap with compute) ----
            short8v nka0, nka1, nva0, nva1;
            unsigned nbb[8];
            if (t < 7) {
                nka0 = *(const short8v*)&Ksh[(t + 1) * 32 + l31][hi * 8];
                nka1 = *(const short8v*)&Ksh[(t + 1) * 32 + l31][16 + hi * 8];
                nva0 = *(const short8v*)&VTsh[l31][(t + 1) * 32 + hi * 8];
                nva1 = *(const short8v*)&VTsh[l31][(t + 1) * 32 + 16 + hi * 8];
#pragma unroll
                for (int n = 0; n < 4; ++n) {
                    int m = ((t + 1) * 32 + n * 8 + hi * 4) >> 1;
                    nbb[2 * n]     = btp[m * 256];
                    nbb[2 * n + 1] = btp[(m + 1) * 256];
                }
            }

            __builtin_amdgcn_s_setprio(1);
            f32x16 s = __builtin_amdgcn_mfma_f32_32x32x16_bf16(ka0, bq0, zero16, 0, 0, 0);
            s = __builtin_amdgcn_mfma_f32_32x32x16_bf16(ka1, bq1, s, 0, 0, 0);
            __builtin_amdgcn_s_setprio(0);

            uint4 w0, w1;
            if (allok) {
                float p0, p1, p2, p3;
                p0 = exp2i(s[0] + lo16f(bb[0])); p1 = exp2i(s[1] + hi16f(bb[0]));
                p2 = exp2i(s[2] + lo16f(bb[1])); p3 = exp2i(s[3] + hi16f(bb[1]));
                ls0 += (p0 + p1) + (p2 + p3);
                w0.x = pk2(p0, p1); w0.y = pk2(p2, p3);
                p0 = exp2i(s[4] + lo16f(bb[2])); p1 = exp2i(s[5] + hi16f(bb[2]));
                p2 = exp2i(s[6] + lo16f(bb[3])); p3 = exp2i(s[7] + hi16f(bb[3]));
                ls1 += (p0 + p1) + (p2 + p3);
                w0.z = pk2(p0, p1); w0.w = pk2(p2, p3);
                p0 = exp2i(s[8] + lo16f(bb[4])); p1 = exp2i(s[9] + hi16f(bb[4]));
                p2 = exp2i(s[10] + lo16f(bb[5])); p3 = exp2i(s[11] + hi16f(bb[5]));
                ls0 += (p0 + p1) + (p2 + p3);
                w1.x = pk2(p0, p1); w1.y = pk2(p2, p3);
                p0 = exp2i(s[12] + lo16f(bb[6])); p1 = exp2i(s[13] + hi16f(bb[6]));
                p2 = exp2i(s[14] + lo16f(bb[7])); p3 = exp2i(s[15] + hi16f(bb[7]));
                ls1 += (p0 + p1) + (p2 + p3);
                w1.z = pk2(p0, p1); w1.w = pk2(p2, p3);
            } else {
#pragma unroll
                for (int n = 0; n < 4; ++n) {
                    f32x4 ma = *(const f32x4*)&pmsh[t * 32 + n * 8 + hi * 4];
                    float p0 = exp2i(rowok ? s[4*n+0] + lo16f(bb[2*n])   + ((ma[0] > 0.5f) ? 0.f : -1e9f) : 0.0f);
                    float p1 = exp2i(rowok ? s[4*n+1] + hi16f(bb[2*n])   + ((ma[1] > 0.5f) ? 0.f : -1e9f) : 0.0f);
                    float p2 = exp2i(rowok ? s[4*n+2] + lo16f(bb[2*n+1]) + ((ma[2] > 0.5f) ? 0.f : -1e9f) : 0.0f);
                    float p3 = exp2i(rowok ? s[4*n+3] + hi16f(bb[2*n+1]) + ((ma[3] > 0.5f) ? 0.f : -1e9f) : 0.0f);
                    ls0 += (p0 + p1) + (p2 + p3);
                    unsigned wa = pk2(p0, p1), wb = pk2(p2, p3);
                    if (n == 0) { w0.x = wa; w0.y = wb; }
                    else if (n == 1) { w0.z = wa; w0.w = wb; }
                    else if (n == 2) { w1.x = wa; w1.y = wb; }
                    else { w1.z = wa; w1.w = wb; }
                }
            }
            short8v pb0 = *(short8v*)&w0;
            short8v pb1 = *(short8v*)&w1;

            __builtin_amdgcn_s_setprio(1);
            oacc = __builtin_amdgcn_mfma_f32_32x32x16_bf16(va0, pb0, oacc, 0, 0, 0);
            oacc = __builtin_amdgcn_mfma_f32_32x32x16_bf16(va1, pb1, oacc, 0, 0, 0);
            __builtin_amdgcn_s_setprio(0);

            if (t < 7) {
                ka0 = nka0; ka1 = nka1; va0 = nva0; va1 = nva1;
#pragma unroll
                for (int e = 0; e < 8; ++e) bb[e] = nbb[e];
            }
        }

        float lsum = ls0 + ls1;
        lsum += __shfl_xor(lsum, 32);
        const float linv = 1.0f / lsum;

        const long orow = (long)(i * 256 + ql) * 128 + h * 32;
#pragma unroll
        for (int n = 0; n < 4; ++n) {
            int dbase = n * 8 + hi * 4;
            float v0 = oacc[4 * n + 0] * linv * h2f(gu[n].x);
            float v1 = oacc[4 * n + 1] * linv * h2f(gu[n].y);
            float v2 = oacc[4 * n + 2] * linv * h2f(gu[n].z);
            float v3 = oacc[4 * n + 3] * linv * h2f(gu[n].w);
            short4 sh = {f2bf(v0), f2bf(v1), f2bf(v2), f2bf(v3)};
            *(short4*)(ob + orow + dbase) = sh;
        }
    }
}

// ---------------------------------------------------------------------------
// KC: out = o @ Wo^T + bo. o single bf16, Wo hi/lo -> 2 MFMAs per fragment.
// ---------------------------------------------------------------------------
__global__ __launch_bounds__(512, 4) void k_outproj(
    const unsigned short* __restrict__ ob,
    const unsigned short* __restrict__ wohi, const unsigned short* __restrict__ wolo,
    const float* __restrict__ bo, float* __restrict__ out)
{
    const int tid  = threadIdx.x;
    const int lane = tid & 63;
    const int wave = tid >> 6;
    const int l15  = lane & 15;
    const int g    = lane >> 4;
    const int wr   = wave >> 2;
    const int wc   = wave & 3;
    const long p0  = (long)blockIdx.x * 128;

    f32x4 acc[4][2];
#pragma unroll
    for (int rt = 0; rt < 4; ++rt) {
        acc[rt][0] = (f32x4){0.f, 0.f, 0.f, 0.f};
        acc[rt][1] = (f32x4){0.f, 0.f, 0.f, 0.f};
    }

#pragma unroll
    for (int ks = 0; ks < 4; ++ks) {
        const int wof = ks * 32 + g * 8;
        short8v bh0 = *(const short8v*)(wohi + (wc * 32 + l15) * 128 + wof);
        short8v bh1 = *(const short8v*)(wohi + (wc * 32 + 16 + l15) * 128 + wof);
        short8v bl0 = *(const short8v*)(wolo + (wc * 32 + l15) * 128 + wof);
        short8v bl1 = *(const short8v*)(wolo + (wc * 32 + 16 + l15) * 128 + wof);
#pragma unroll
        for (int rt = 0; rt < 4; ++rt) {
            long aoff = (p0 + wr * 64 + rt * 16 + l15) * 128 + ks * 32 + g * 8;
            short8v ah = *(const short8v*)(ob + aoff);
            acc[rt][0] = __builtin_amdgcn_mfma_f32_16x16x32_bf16(ah, bh0, acc[rt][0], 0, 0, 0);
            acc[rt][0] = __builtin_amdgcn_mfma_f32_16x16x32_bf16(ah, bl0, acc[rt][0], 0, 0, 0);
            acc[rt][1] = __builtin_amdgcn_mfma_f32_16x16x32_bf16(ah, bh1, acc[rt][1], 0, 0, 0);
            acc[rt][1] = __builtin_amdgcn_mfma_f32_16x16x32_bf16(ah, bl1, acc[rt][1], 0, 0, 0);
        }
    }

#pragma unroll
    for (int ct = 0; ct < 2; ++ct) {
        float bv = bo[wc * 32 + ct * 16 + l15];
#pragma unroll
        for (int rt = 0; rt < 4; ++rt)
#pragma unroll
            for (int r = 0; r < 4; ++r)
                out[(p0 + wr * 64 + rt * 16 + g * 4 + r) * 128 +
                    wc * 32 + ct * 16 + l15] = acc[rt][ct][r] + bv;
    }
}

// ---------------------------------------------------------------------------
extern "C" void kernel_launch(void* const* d_in, const int* in_sizes, int n_in,
                              void* d_out, int out_size, void* d_ws, size_t ws_size,
                              hipStream_t stream) {
    const float* z   = (const float*)d_in[0];
    const float* pm  = (const float*)d_in[1];
    const float* lnw = (const float*)d_in[2];
    const float* lnb = (const float*)d_in[3];
    const float* Wq  = (const float*)d_in[4];
    const float* Wk  = (const float*)d_in[5];
    const float* Wv  = (const float*)d_in[6];
    const float* Wb  = (const float*)d_in[7];
    const float* Wg  = (const float*)d_in[8];
    const float* bg  = (const float*)d_in[9];
    const float* Wo  = (const float*)d_in[10];
    const float* bo  = (const float*)d_in[11];
    float* out = (float*)d_out;

    unsigned short* wsS  = (unsigned short*)d_ws;
    unsigned short* wbf  = wsS;                   // 65536
    unsigned short* wbbf = wsS + 65536;           // 512
    unsigned short* wohi = wsS + 66048;           // 16384
    unsigned short* wolo = wsS + 82432;           // 16384
    unsigned* bTP        = (unsigned*)(wsS + 98816);  // 131072 uints [4][128][256]
    unsigned short* qb   = wsS + 360960;          // 8388608 bf16 [4][65536][32]
    unsigned short* kb   = qb + 8388608;
    unsigned short* vtb  = kb + 8388608;          // [4][256][32][256] (perm keys)
    unsigned short* obw  = vtb + 8388608;         // 8388608 bf16 [65536][128]
    unsigned short* ghw  = obw + 8388608;         // 8388608 fp16 [4][65536][32]

    k_wprep<<<322, 256, 0, stream>>>(Wq, Wk, Wv, Wg, Wb, Wo, wbf, wbbf, wohi, wolo);
    k_lnproj<<<512, 512, 0, stream>>>(z, lnw, lnb, wbf, wbbf, bg, qb, kb, vtb, ghw, bTP);
    k_attn_mfma<<<1024, 256, 0, stream>>>(qb, kb, vtb, ghw, bTP, pm, obw);
    k_outproj<<<512, 512, 0, stream>>>(obw, wohi, wolo, bo, out);
}